// Round 4
// baseline (303.477 us; speedup 1.0000x reference)
//
#include <hip/hip_runtime.h>
#include <hip/hip_bf16.h>
#include <hip/hip_cooperative_groups.h>

namespace cg = cooperative_groups;

// Problem constants
#define BATCH     512
#define IMG       128
#define PS        8
#define GRID_P    16      // IMG/PS
#define NP        256     // GRID_P*GRID_P
#define C         128     // BOND_DIM
#define R         64      // CP_RANK
#define E         512     // EMBED_DIM

typedef float f32x4 __attribute__((ext_vector_type(4)));
typedef short s16x8 __attribute__((ext_vector_type(8)));

__device__ __forceinline__ unsigned short f2bf(float x) {
    unsigned int u = __float_as_uint(x);
    u += 0x7fffu + ((u >> 16) & 1u);          // RNE
    return (unsigned short)(u >> 16);
}

// ---------------------------------------------------------------------------
// ONE cooperative kernel, grid = 512 blocks x 256 threads, 2 blocks/CU
// (LDS arena 59,392 B <= 80 KB; __launch_bounds__(256,2) caps VGPR at 256
//  -> 2 waves/SIMD -> exactly 2 blocks/CU -> grid co-resident).
//
// Phase 0 (all 512): issue x pixel-fragment loads into registers (independent
//          of prep output; streams x's 33.5 MB during phase P).
// Phase P (blocks 0..432): prep work (WfT/pf from f0+Wp; fTL/oT/WhT
//          transposes). Blocks 433..511 idle to the sync.
// grid.sync()   -- replaces kernel boundary #1 (visibility of WfT/pf/fTL/oT)
// Phase L (all 512): level0+level1 fused, stage-free, -> h2.
// grid.sync()   -- replaces kernel boundary #2 (visibility of h2)
// Phase T (blocks 0..31): level2+level3+LN+head+L2norm -> out. Rest exit.
// ---------------------------------------------------------------------------
__global__ __launch_bounds__(256, 2) void mega_kernel(
    const float* __restrict__ x,     const float* __restrict__ Wp,
    const float* __restrict__ bp,    const float* __restrict__ pos,
    const float* __restrict__ gamma, const float* __restrict__ beta,
    const float* __restrict__ Wh,    const float* __restrict__ bh,
    const float* __restrict__ f0,    const float* __restrict__ o0,
    const float* __restrict__ f1,    const float* __restrict__ o1,
    const float* __restrict__ f2,    const float* __restrict__ o2,
    const float* __restrict__ f3,    const float* __restrict__ o3,
    unsigned short* __restrict__ ws, float* __restrict__ out)
{
    // ---- workspace layout (bf16 elements unless noted) ----
    unsigned short* h2  = ws;                             // 1,048,576
    unsigned short* fTL = h2 + (size_t)1048576;           //   688,128 (84 slices)
    unsigned short* oT  = fTL + (size_t)688128;           //   696,320 (85 slices)
    unsigned short* WfT = oT + (size_t)696320;            // 1,048,576 (256 x 64x64)
    unsigned short* WhT = WfT + (size_t)1048576;          //    65,536
    float*          pf  = (float*)(WhT + 65536);          //    16,384 fp32
    unsigned short* fT1 = fTL;
    unsigned short* fT2 = fTL + (size_t)64 * 8192;
    unsigned short* fT3 = fTL + (size_t)80 * 8192;
    unsigned short* oT2 = oT + (size_t)80 * 8192;
    unsigned short* oT3 = oT + (size_t)84 * 8192;

    // ---- LDS arena, aliased per phase ----
    __shared__ __align__(16) char smem[59392];
    // phase P views
    float*          ls   = (float*)         (smem);            // 34816 B
    float*          redp = (float*)         (smem + 34816);    //  1024 B
    // phase L views
    float*          us1  = (float*)         (smem);            // 17408 B
    unsigned short* ps0  = (unsigned short*)(smem + 17408);    //  9216 B
    unsigned short* ps1  = (unsigned short*)(smem + 26624);    //  2304 B
    unsigned short* h1s  = (unsigned short*)(smem + 28928);    // 17408 B
    // phase T views
    float*          us3  = (float*)         (smem);            // 17408 B
    unsigned short* ps2  = (unsigned short*)(smem + 17408);    //  9216 B
    unsigned short* ps3  = (unsigned short*)(smem + 26624);    //  2304 B
    unsigned short* h3s  = (unsigned short*)(smem + 28928);    // 17408 B
    float*          h4s  = (float*)         (smem + 46336);    //  8448 B
    unsigned short* hns  = (unsigned short*)(smem + 54784);    //  4352 B
    float*          redt = (float*)         (smem + 59136);    //   256 B

    cg::grid_group grid = cg::this_grid();

    const int bi = blockIdx.x, t = threadIdx.x;
    const int w = t >> 6, lane = t & 63;
    const int m = lane & 15, g = lane >> 4;

    // level01 geometry (all 512 blocks)
    const int n1 = bi >> 5, btile = bi & 31;
    const int btL = btile * 16;
    const int y1g = n1 >> 2, x1g = n1 & 3;
    const int Ry0 = y1g * 32, Rx0 = x1g * 32;
    const int n0 = (2 * y1g + (w >> 1)) * 8 + 2 * x1g + (w & 1);

    // ================= Phase 0: x pixel fragments -> registers =============
    // a[q][kt][e] = bf16( x[btL+m][Ry0+rq+kt*4][Rx0+cc+e] ). Independent of
    // phase P; loads stream during prep. Bit-identical to staged variants.
    s16x8 a[4][2];
    {
        const int rbase = 16 * (w >> 1);
        const int cbase = 16 * (w & 1);
        const float* xb = x + (size_t)(btL + m) * (IMG * IMG);
#pragma unroll
        for (int q = 0; q < 4; ++q) {
            const int rq = rbase + 8 * (q >> 1) + g;
            const int cc = cbase + 8 * (q & 1);
#pragma unroll
            for (int kt = 0; kt < 2; ++kt) {
                const float* px = xb + (size_t)(Ry0 + rq + kt * 4) * IMG + Rx0 + cc;
                const float4 p0 = *(const float4*)px;
                const float4 p1 = *(const float4*)(px + 4);
                s16x8 fr;
                fr[0] = (short)f2bf(p0.x); fr[1] = (short)f2bf(p0.y);
                fr[2] = (short)f2bf(p0.z); fr[3] = (short)f2bf(p0.w);
                fr[4] = (short)f2bf(p1.x); fr[5] = (short)f2bf(p1.y);
                fr[6] = (short)f2bf(p1.z); fr[7] = (short)f2bf(p1.w);
                a[q][kt] = fr;
            }
        }
    }

    // ================= Phase P: prep (blocks 0..432) ========================
    if (bi < 256) {
        const float* src = f0 + (size_t)bi * 8192;
#pragma unroll
        for (int i = 0; i < 8; ++i) {
            const int fi = (t + 256 * i) * 4;
            const int c = fi >> 6, r = fi & 63;      // in[c][r]
            *(float4*)(ls + c * 68 + r) = *(const float4*)(src + fi);
        }
        __syncthreads();

        f32x4 acc[4];
#pragma unroll
        for (int nt = 0; nt < 4; ++nt) acc[nt] = (f32x4){0.f, 0.f, 0.f, 0.f};
#pragma unroll
        for (int kt = 0; kt < 4; ++kt) {
            s16x8 afr;
#pragma unroll
            for (int e = 0; e < 8; ++e)
                afr[e] = (short)f2bf(ls[(kt * 32 + g * 8 + e) * 68 + w * 16 + m]);
#pragma unroll
            for (int nt = 0; nt < 4; ++nt) {
                const float* wr = Wp + (size_t)(nt * 16 + m) * 128 + kt * 32 + g * 8;
                const float4 b0 = *(const float4*)wr;
                const float4 b1 = *(const float4*)(wr + 4);
                s16x8 bfr;
                bfr[0] = (short)f2bf(b0.x); bfr[1] = (short)f2bf(b0.y);
                bfr[2] = (short)f2bf(b0.z); bfr[3] = (short)f2bf(b0.w);
                bfr[4] = (short)f2bf(b1.x); bfr[5] = (short)f2bf(b1.y);
                bfr[6] = (short)f2bf(b1.z); bfr[7] = (short)f2bf(b1.w);
                acc[nt] = __builtin_amdgcn_mfma_f32_16x16x32_bf16(afr, bfr, acc[nt], 0, 0, 0);
            }
        }
        unsigned short* D = WfT + (size_t)bi * 4096;
#pragma unroll
        for (int nt = 0; nt < 4; ++nt)
#pragma unroll
            for (int j = 0; j < 4; ++j)
                D[(size_t)(w * 16 + g * 4 + j) * 64 + nt * 16 + m] = f2bf(acc[nt][j]);

        {
            const int r = t & 63, half = t >> 6;
            const int nn = bi >> 2, q = bi & 3;
            const int pp = (2 * (nn >> 3) + (q >> 1)) * GRID_P + 2 * (nn & 7) + (q & 1);
            const float* posr = pos + (size_t)pp * C;
            float s = 0.f;
#pragma unroll 8
            for (int e = 0; e < 32; ++e) {
                const int c = half * 32 + e;
                s += (posr[c] + bp[c]) * ls[c * 68 + r];
            }
            redp[r * 4 + half] = s;
        }
        __syncthreads();
        if (t < 64)
            pf[bi * 64 + t] = redp[t * 4 + 0] + redp[t * 4 + 1] + redp[t * 4 + 2] + redp[t * 4 + 3];
    } else if (bi < 340) {
        const int ti = bi - 256;
        const float* src;
        if      (ti < 64) src = f1 + (size_t)ti * 8192;
        else if (ti < 80) src = f2 + (size_t)(ti - 64) * 8192;
        else              src = f3 + (size_t)(ti - 80) * 8192;
        unsigned short* dst = fTL + (size_t)ti * 8192;
#pragma unroll
        for (int i = 0; i < 8; ++i) {
            const int fi = (t + 256 * i) * 4;
            const int c = fi >> 6, r = fi & 63;
            *(float4*)(ls + c * 68 + r) = *(const float4*)(src + fi);
        }
        __syncthreads();
        const int rr = t >> 2, seg = t & 3;
        unsigned int* d32 = (unsigned int*)(dst + rr * 128 + seg * 32);
#pragma unroll
        for (int ii = 0; ii < 16; ++ii) {
            const int c = seg * 32 + ii * 2;
            const unsigned int lo = f2bf(ls[c * 68 + rr]);
            const unsigned int hi = f2bf(ls[(c + 1) * 68 + rr]);
            d32[ii] = lo | (hi << 16);
        }
    } else if (bi < 425) {
        const int oi = bi - 340;
        const float* src;
        if      (oi < 64) src = o0 + (size_t)oi * 8192;
        else if (oi < 80) src = o1 + (size_t)(oi - 64) * 8192;
        else if (oi < 84) src = o2 + (size_t)(oi - 80) * 8192;
        else              src = o3 + (size_t)(oi - 84) * 8192;
        unsigned short* dst = oT + (size_t)oi * 8192;
#pragma unroll
        for (int i = 0; i < 8; ++i) {
            const int fi = (t + 256 * i) * 4;
            const int r = fi >> 7, c = fi & 127;
            *(float4*)(ls + r * 132 + c) = *(const float4*)(src + fi);
        }
        __syncthreads();
        const int cc = t >> 1, seg = t & 1;
        unsigned int* d32 = (unsigned int*)(dst + cc * 64 + seg * 32);
#pragma unroll
        for (int ii = 0; ii < 16; ++ii) {
            const int r = seg * 32 + ii * 2;
            const unsigned int lo = f2bf(ls[r * 132 + cc]);
            const unsigned int hi = f2bf(ls[(r + 1) * 132 + cc]);
            d32[ii] = lo | (hi << 16);
        }
    } else if (bi < 433) {
        const int j = bi - 425;
#pragma unroll
        for (int i = 0; i < 8; ++i) {
            const int fi = (t + 256 * i) * 4;
            const int c = fi >> 6, e = fi & 63;
            *(float4*)(ls + c * 68 + e) = *(const float4*)(Wh + (size_t)c * E + j * 64 + e);
        }
        __syncthreads();
        const int rr = t >> 2, seg = t & 3;
        unsigned int* d32 = (unsigned int*)(WhT + (size_t)(j * 64 + rr) * 128 + seg * 32);
#pragma unroll
        for (int ii = 0; ii < 16; ++ii) {
            const int c = seg * 32 + ii * 2;
            const unsigned int lo = f2bf(ls[c * 68 + rr]);
            const unsigned int hi = f2bf(ls[(c + 1) * 68 + rr]);
            d32[ii] = lo | (hi << 16);
        }
    }
    // blocks 433..511: no prep work

    grid.sync();   // WfT/pf/fTL/oT/WhT now visible grid-wide

    // ================= Phase L: level0 + level1 (all 512 blocks) ===========
    {
        // ---- level0 u-phase (+pf init), all 4 quadrants in-wave ----
        f32x4 accu[4][4];
#pragma unroll
        for (int q = 0; q < 4; ++q) {
            const float* pfq = pf + (size_t)(n0 * 4 + q) * 64;
#pragma unroll
            for (int nt = 0; nt < 4; ++nt) {
                const float pv = pfq[nt * 16 + m];
                accu[q][nt] = (f32x4){pv, pv, pv, pv};
            }
        }
#pragma unroll
        for (int q = 0; q < 4; ++q) {
            const unsigned short* Wq = WfT + (size_t)(n0 * 4 + q) * 4096;
#pragma unroll
            for (int kt = 0; kt < 2; ++kt) {
                const int koff = kt * 32 + g * 8;
#pragma unroll
                for (int nt = 0; nt < 4; ++nt) {
                    const s16x8 bfr = *(const s16x8*)(Wq + (size_t)(nt * 16 + m) * 64 + koff);
                    accu[q][nt] = __builtin_amdgcn_mfma_f32_16x16x32_bf16(a[q][kt], bfr, accu[q][nt], 0, 0, 0);
                }
            }
        }

        // ---- level0 p-phase (regs) + wave-private ps roundtrip ----
        unsigned short* myps = ps0 + w * (16 * 72);
#pragma unroll
        for (int nt = 0; nt < 4; ++nt) {
            const f32x4 pr = accu[0][nt] * accu[1][nt] * accu[2][nt] * accu[3][nt];
#pragma unroll
            for (int j = 0; j < 4; ++j)
                myps[(g * 4 + j) * 72 + nt * 16 + m] = f2bf(pr[j]);
        }

        // ---- level0 o-phase (in-wave) -> h1 tile in wave-private LDS ----
        {
            s16x8 ap[2];
#pragma unroll
            for (int kt = 0; kt < 2; ++kt)
                ap[kt] = *(const s16x8*)(myps + m * 72 + kt * 32 + g * 8);
            const unsigned short* oTn = oT + (size_t)n0 * 8192;
            unsigned short* myh = h1s + w * (16 * 136);
#pragma unroll
            for (int ct = 0; ct < 8; ++ct) {
                f32x4 aco = (f32x4){0.f, 0.f, 0.f, 0.f};
#pragma unroll
                for (int kt = 0; kt < 2; ++kt) {
                    const s16x8 bfr = *(const s16x8*)(oTn + (size_t)(ct * 16 + m) * 64 + kt * 32 + g * 8);
                    aco = __builtin_amdgcn_mfma_f32_16x16x32_bf16(ap[kt], bfr, aco, 0, 0, 0);
                }
#pragma unroll
                for (int j = 0; j < 4; ++j)
                    myh[(g * 4 + j) * 136 + ct * 16 + m] = f2bf(aco[j]);
            }
        }

        // ---- level1 u-phase: A = own h1 tile (wave-private, no barrier) ----
        {
            const unsigned short* myh = h1s + w * (16 * 136);
            const unsigned short* fq = fT1 + (size_t)(n1 * 4 + w) * 8192;
            f32x4 au[4];
#pragma unroll
            for (int nt = 0; nt < 4; ++nt) au[nt] = (f32x4){0.f, 0.f, 0.f, 0.f};
#pragma unroll
            for (int kt = 0; kt < 4; ++kt) {
                const int koff = kt * 32 + g * 8;
                const s16x8 afr = *(const s16x8*)(myh + m * 136 + koff);
#pragma unroll
                for (int nt = 0; nt < 4; ++nt) {
                    const s16x8 bfr = *(const s16x8*)(fq + (size_t)(nt * 16 + m) * 128 + koff);
                    au[nt] = __builtin_amdgcn_mfma_f32_16x16x32_bf16(afr, bfr, au[nt], 0, 0, 0);
                }
            }
#pragma unroll
            for (int nt = 0; nt < 4; ++nt)
#pragma unroll
                for (int j = 0; j < 4; ++j)
                    us1[(w * 16 + g * 4 + j) * 68 + nt * 16 + m] = au[nt][j];
        }
        __syncthreads();

        // ---- level1 p-phase (block-wide) ----
        {
            const int pb = t >> 4, r0 = (t & 15) * 4;
            const f32x4 u0 = *(const f32x4*)(us1 + (0 * 16 + pb) * 68 + r0);
            const f32x4 u1 = *(const f32x4*)(us1 + (1 * 16 + pb) * 68 + r0);
            const f32x4 u2 = *(const f32x4*)(us1 + (2 * 16 + pb) * 68 + r0);
            const f32x4 u3 = *(const f32x4*)(us1 + (3 * 16 + pb) * 68 + r0);
            const f32x4 p = u0 * u1 * u2 * u3;
            uint2 v;
            v.x = (unsigned int)f2bf(p[0]) | ((unsigned int)f2bf(p[1]) << 16);
            v.y = (unsigned int)f2bf(p[2]) | ((unsigned int)f2bf(p[3]) << 16);
            *(uint2*)(ps1 + pb * 72 + r0) = v;
        }
        __syncthreads();

        // ---- level1 o-phase: wave handles ct = 2w, 2w+1 -> h2 ----
        {
            s16x8 ap[2];
#pragma unroll
            for (int kt = 0; kt < 2; ++kt)
                ap[kt] = *(const s16x8*)(ps1 + m * 72 + kt * 32 + g * 8);
            const unsigned short* oTn = oT + (size_t)(64 + n1) * 8192;
#pragma unroll
            for (int i = 0; i < 2; ++i) {
                const int ct = w * 2 + i;
                f32x4 aco = (f32x4){0.f, 0.f, 0.f, 0.f};
#pragma unroll
                for (int kt = 0; kt < 2; ++kt) {
                    const s16x8 bfr = *(const s16x8*)(oTn + (size_t)(ct * 16 + m) * 64 + kt * 32 + g * 8);
                    aco = __builtin_amdgcn_mfma_f32_16x16x32_bf16(ap[kt], bfr, aco, 0, 0, 0);
                }
#pragma unroll
                for (int j = 0; j < 4; ++j)
                    h2[((size_t)(btL + g * 4 + j) * 16 + n1) * C + ct * 16 + m] = f2bf(aco[j]);
            }
        }
    }

    grid.sync();   // h2 now visible grid-wide

    // ================= Phase T: tail (blocks 0..31) ========================
    if (bi >= 32) return;
    const int bt = bi * 16;

    // ===== Level 2: wave w = node n2 =====
    {
        const int n2 = w;
        const int y1 = n2 >> 1, x1 = n2 & 1;

        s16x8 xa[4][4];    // [q][kt]
#pragma unroll
        for (int q = 0; q < 4; ++q) {
            const int pidx = (2 * y1 + (q >> 1)) * 4 + 2 * x1 + (q & 1);
            const unsigned short* xq = h2 + ((size_t)(bt + m) * 16 + pidx) * C;
#pragma unroll
            for (int kt = 0; kt < 4; ++kt)
                xa[q][kt] = *(const s16x8*)(xq + kt * 32 + g * 8);
        }

        f32x4 acc_u[4][4];
#pragma unroll
        for (int q = 0; q < 4; ++q)
#pragma unroll
            for (int nt = 0; nt < 4; ++nt) acc_u[q][nt] = (f32x4){0.f, 0.f, 0.f, 0.f};
#pragma unroll
        for (int q = 0; q < 4; ++q) {
            const unsigned short* fq = fT2 + (size_t)(n2 * 4 + q) * R * C;
#pragma unroll
            for (int kt = 0; kt < 4; ++kt) {
                const int koff = kt * 32 + g * 8;
#pragma unroll
                for (int nt = 0; nt < 4; ++nt) {
                    const s16x8 bfr = *(const s16x8*)(fq + (size_t)(nt * 16 + m) * C + koff);
                    acc_u[q][nt] = __builtin_amdgcn_mfma_f32_16x16x32_bf16(xa[q][kt], bfr, acc_u[q][nt], 0, 0, 0);
                }
            }
        }

        s16x8 ob[8][2];
        {
            const unsigned short* oTn = oT2 + (size_t)n2 * C * R;
#pragma unroll
            for (int ct = 0; ct < 8; ++ct)
#pragma unroll
                for (int kt = 0; kt < 2; ++kt)
                    ob[ct][kt] = *(const s16x8*)(oTn + (size_t)(ct * 16 + m) * R + kt * 32 + g * 8);
        }

        unsigned short* myps2 = ps2 + w * 16 * 72;
#pragma unroll
        for (int nt = 0; nt < 4; ++nt) {
            const f32x4 p = acc_u[0][nt] * acc_u[1][nt] * acc_u[2][nt] * acc_u[3][nt];
#pragma unroll
            for (int j = 0; j < 4; ++j)
                myps2[(g * 4 + j) * 72 + nt * 16 + m] = f2bf(p[j]);
        }
        f32x4 aco[8];
#pragma unroll
        for (int ct = 0; ct < 8; ++ct) aco[ct] = (f32x4){0.f, 0.f, 0.f, 0.f};
#pragma unroll
        for (int kt = 0; kt < 2; ++kt) {
            const int koff = kt * 32 + g * 8;
            const s16x8 av = *(const s16x8*)(myps2 + m * 72 + koff);
#pragma unroll
            for (int ct = 0; ct < 8; ++ct)
                aco[ct] = __builtin_amdgcn_mfma_f32_16x16x32_bf16(av, ob[ct][kt], aco[ct], 0, 0, 0);
        }
#pragma unroll
        for (int ct = 0; ct < 8; ++ct)
#pragma unroll
            for (int j = 0; j < 4; ++j)
                h3s[((g * 4 + j) * 4 + n2) * 136 + ct * 16 + m] = f2bf(aco[ct][j]);
    }
    __syncthreads();

    // ===== Level 3: wave w = quadrant q =====
    {
        const int q = w;
        s16x8 fb[4][4];   // [kt][nt]
        {
            const unsigned short* fq = fT3 + (size_t)q * R * C;
#pragma unroll
            for (int kt = 0; kt < 4; ++kt)
#pragma unroll
                for (int nt = 0; nt < 4; ++nt)
                    fb[kt][nt] = *(const s16x8*)(fq + (size_t)(nt * 16 + m) * C + kt * 32 + g * 8);
        }
        f32x4 acc_u[4];
#pragma unroll
        for (int nt = 0; nt < 4; ++nt) acc_u[nt] = (f32x4){0.f, 0.f, 0.f, 0.f};
#pragma unroll
        for (int kt = 0; kt < 4; ++kt) {
            const int koff = kt * 32 + g * 8;
            const s16x8 av = *(const s16x8*)(h3s + (m * 4 + q) * 136 + koff);
#pragma unroll
            for (int nt = 0; nt < 4; ++nt)
                acc_u[nt] = __builtin_amdgcn_mfma_f32_16x16x32_bf16(av, fb[kt][nt], acc_u[nt], 0, 0, 0);
        }
#pragma unroll
        for (int nt = 0; nt < 4; ++nt)
#pragma unroll
            for (int j = 0; j < 4; ++j)
                us3[(q * 16 + g * 4 + j) * 68 + nt * 16 + m] = acc_u[nt][j];
    }
    __syncthreads();
    {
        const int pb = t >> 4, r0 = (t & 15) * 4;
        const f32x4 u0 = *(const f32x4*)(us3 + (0 * 16 + pb) * 68 + r0);
        const f32x4 u1 = *(const f32x4*)(us3 + (1 * 16 + pb) * 68 + r0);
        const f32x4 u2 = *(const f32x4*)(us3 + (2 * 16 + pb) * 68 + r0);
        const f32x4 u3 = *(const f32x4*)(us3 + (3 * 16 + pb) * 68 + r0);
        const f32x4 p = u0 * u1 * u2 * u3;
        uint2 v;
        v.x = (unsigned int)f2bf(p[0]) | ((unsigned int)f2bf(p[1]) << 16);
        v.y = (unsigned int)f2bf(p[2]) | ((unsigned int)f2bf(p[3]) << 16);
        *(uint2*)(ps3 + pb * 72 + r0) = v;
    }
    __syncthreads();
    {
        s16x8 ap[2];
#pragma unroll
        for (int kt = 0; kt < 2; ++kt)
            ap[kt] = *(const s16x8*)(ps3 + m * 72 + kt * 32 + g * 8);
#pragma unroll
        for (int i = 0; i < 2; ++i) {
            f32x4 aco = (f32x4){0.f, 0.f, 0.f, 0.f};
            const int ct = w * 2 + i;
#pragma unroll
            for (int kt = 0; kt < 2; ++kt) {
                const s16x8 bfr = *(const s16x8*)(oT3 + (size_t)(ct * 16 + m) * R + kt * 32 + g * 8);
                aco = __builtin_amdgcn_mfma_f32_16x16x32_bf16(ap[kt], bfr, aco, 0, 0, 0);
            }
#pragma unroll
            for (int j = 0; j < 4; ++j)
                h4s[(g * 4 + j) * 132 + ct * 16 + m] = aco[j];
        }
    }
    __syncthreads();

    // ===== LayerNorm =====
    {
        const int rb = w * 4 + g;
        const int c0 = m * 8;
        const f32x4 v0 = *(const f32x4*)(h4s + rb * 132 + c0);
        const f32x4 v1 = *(const f32x4*)(h4s + rb * 132 + c0 + 4);
        float s  = v0[0] + v0[1] + v0[2] + v0[3] + v1[0] + v1[1] + v1[2] + v1[3];
        float ss = v0[0]*v0[0] + v0[1]*v0[1] + v0[2]*v0[2] + v0[3]*v0[3]
                 + v1[0]*v1[0] + v1[1]*v1[1] + v1[2]*v1[2] + v1[3]*v1[3];
#pragma unroll
        for (int off = 1; off < 16; off <<= 1) {
            s  += __shfl_xor(s, off);
            ss += __shfl_xor(ss, off);
        }
        const float mu   = s * (1.f / C);
        const float var  = ss * (1.f / C) - mu * mu;
        const float rstd = rsqrtf(var + 1e-5f);
        const f32x4 ga0 = *(const f32x4*)(gamma + c0);
        const f32x4 ga1 = *(const f32x4*)(gamma + c0 + 4);
        const f32x4 be0 = *(const f32x4*)(beta + c0);
        const f32x4 be1 = *(const f32x4*)(beta + c0 + 4);
        unsigned int o32[4];
        float hv[8];
#pragma unroll
        for (int k = 0; k < 4; ++k) hv[k]     = (v0[k] - mu) * rstd * ga0[k] + be0[k];
#pragma unroll
        for (int k = 0; k < 4; ++k) hv[4 + k] = (v1[k] - mu) * rstd * ga1[k] + be1[k];
#pragma unroll
        for (int k = 0; k < 4; ++k)
            o32[k] = (unsigned int)f2bf(hv[2*k]) | ((unsigned int)f2bf(hv[2*k+1]) << 16);
        *(uint4*)(hns + rb * 136 + c0) = *(uint4*)o32;
    }
    __syncthreads();

    // ===== Head GEMM + L2 norm =====
    {
        f32x4 acc[8];
#pragma unroll
        for (int nt = 0; nt < 8; ++nt) {
            const int e = w * 128 + nt * 16 + m;
            const float bv = bh[e];
            acc[nt] = (f32x4){bv, bv, bv, bv};
        }
#pragma unroll
        for (int kt = 0; kt < 4; ++kt) {
            const int koff = kt * 32 + g * 8;
            const s16x8 av = *(const s16x8*)(hns + m * 136 + koff);
#pragma unroll
            for (int nt = 0; nt < 8; ++nt) {
                const int e = w * 128 + nt * 16 + m;
                const s16x8 bfr = *(const s16x8*)(WhT + (size_t)e * 128 + koff);
                acc[nt] = __builtin_amdgcn_mfma_f32_16x16x32_bf16(av, bfr, acc[nt], 0, 0, 0);
            }
        }
        float sq[4];
#pragma unroll
        for (int j = 0; j < 4; ++j) {
            float s = 0.f;
#pragma unroll
            for (int nt = 0; nt < 8; ++nt) s += acc[nt][j] * acc[nt][j];
#pragma unroll
            for (int off = 1; off < 16; off <<= 1) s += __shfl_xor(s, off);
            sq[j] = s;
        }
        if (m == 0) {
#pragma unroll
            for (int j = 0; j < 4; ++j) redt[(g * 4 + j) * 4 + w] = sq[j];
        }
        __syncthreads();
#pragma unroll
        for (int j = 0; j < 4; ++j) {
            const int row = g * 4 + j;
            const float tot = redt[row * 4 + 0] + redt[row * 4 + 1]
                            + redt[row * 4 + 2] + redt[row * 4 + 3];
            const float inv = 1.f / fmaxf(sqrtf(tot), 1e-12f);
#pragma unroll
            for (int nt = 0; nt < 8; ++nt) {
                const int e = w * 128 + nt * 16 + m;
                out[(size_t)(bt + row) * E + e] = acc[nt][j] * inv;
            }
        }
    }
}

// ---------------------------------------------------------------------------
extern "C" void kernel_launch(void* const* d_in, const int* in_sizes, int n_in,
                              void* d_out, int out_size, void* d_ws, size_t ws_size,
                              hipStream_t stream) {
    const float* x     = (const float*)d_in[0];
    const float* Wp    = (const float*)d_in[1];
    const float* bp    = (const float*)d_in[2];
    const float* pos   = (const float*)d_in[3];
    const float* gamma = (const float*)d_in[4];
    const float* beta  = (const float*)d_in[5];
    const float* Wh    = (const float*)d_in[6];
    const float* bh    = (const float*)d_in[7];
    const float* f0    = (const float*)d_in[8];
    const float* o0    = (const float*)d_in[9];
    const float* f1    = (const float*)d_in[10];
    const float* o1    = (const float*)d_in[11];
    const float* f2    = (const float*)d_in[12];
    const float* o2    = (const float*)d_in[13];
    const float* f3    = (const float*)d_in[14];
    const float* o3    = (const float*)d_in[15];
    unsigned short* ws = (unsigned short*)d_ws;
    float* out = (float*)d_out;

    void* kargs[] = {
        (void*)&x, (void*)&Wp, (void*)&bp, (void*)&pos,
        (void*)&gamma, (void*)&beta, (void*)&Wh, (void*)&bh,
        (void*)&f0, (void*)&o0, (void*)&f1, (void*)&o1,
        (void*)&f2, (void*)&o2, (void*)&f3, (void*)&o3,
        (void*)&ws, (void*)&out
    };
    hipLaunchCooperativeKernel((const void*)mega_kernel,
                               dim3(512), dim3(256), kargs, 0, stream);
}

// Round 5
// 180.636 us; speedup vs baseline: 1.6800x; 1.6800x over previous
//
#include <hip/hip_runtime.h>
#include <hip/hip_bf16.h>

// Problem constants
#define BATCH     512
#define IMG       128
#define PS        8
#define GRID_P    16      // IMG/PS
#define NP        256     // GRID_P*GRID_P
#define C         128     // BOND_DIM
#define R         64      // CP_RANK
#define E         512     // EMBED_DIM

typedef float f32x4 __attribute__((ext_vector_type(4)));
typedef short s16x8 __attribute__((ext_vector_type(8)));

__device__ __forceinline__ unsigned short f2bf(float x) {
    unsigned int u = __float_as_uint(x);
    u += 0x7fffu + ((u >> 16) & 1u);          // RNE
    return (unsigned short)(u >> 16);
}

// ---------------------------------------------------------------------------
// prep_all (ONE launch, 433 blocks) -- unchanged from R3.
// ---------------------------------------------------------------------------
__global__ __launch_bounds__(256) void prep_all_kernel(
    const float* __restrict__ f0, const float* __restrict__ f1,
    const float* __restrict__ f2, const float* __restrict__ f3,
    const float* __restrict__ o0, const float* __restrict__ o1,
    const float* __restrict__ o2, const float* __restrict__ o3,
    const float* __restrict__ Wh, const float* __restrict__ Wp,
    const float* __restrict__ pos, const float* __restrict__ bp,
    unsigned short* __restrict__ fTL, unsigned short* __restrict__ oT,
    unsigned short* __restrict__ WhT, unsigned short* __restrict__ WfT,
    float* __restrict__ pf)
{
    __shared__ float ls[128 * 68];    // 34.8 KB
    __shared__ float red[64 * 4];
    const int bi = blockIdx.x, t = threadIdx.x;

    if (bi < 256) {
        const float* src = f0 + (size_t)bi * 8192;
#pragma unroll
        for (int i = 0; i < 8; ++i) {
            const int fi = (t + 256 * i) * 4;
            const int c = fi >> 6, r = fi & 63;      // in[c][r]
            *(float4*)(ls + c * 68 + r) = *(const float4*)(src + fi);
        }
        __syncthreads();

        const int w = t >> 6, lane = t & 63;
        const int m = lane & 15, g = lane >> 4;

        f32x4 acc[4];
#pragma unroll
        for (int nt = 0; nt < 4; ++nt) acc[nt] = (f32x4){0.f, 0.f, 0.f, 0.f};
#pragma unroll
        for (int kt = 0; kt < 4; ++kt) {
            s16x8 afr;
#pragma unroll
            for (int e = 0; e < 8; ++e)
                afr[e] = (short)f2bf(ls[(kt * 32 + g * 8 + e) * 68 + w * 16 + m]);
#pragma unroll
            for (int nt = 0; nt < 4; ++nt) {
                const float* wr = Wp + (size_t)(nt * 16 + m) * 128 + kt * 32 + g * 8;
                const float4 b0 = *(const float4*)wr;
                const float4 b1 = *(const float4*)(wr + 4);
                s16x8 bfr;
                bfr[0] = (short)f2bf(b0.x); bfr[1] = (short)f2bf(b0.y);
                bfr[2] = (short)f2bf(b0.z); bfr[3] = (short)f2bf(b0.w);
                bfr[4] = (short)f2bf(b1.x); bfr[5] = (short)f2bf(b1.y);
                bfr[6] = (short)f2bf(b1.z); bfr[7] = (short)f2bf(b1.w);
                acc[nt] = __builtin_amdgcn_mfma_f32_16x16x32_bf16(afr, bfr, acc[nt], 0, 0, 0);
            }
        }
        unsigned short* D = WfT + (size_t)bi * 4096;
#pragma unroll
        for (int nt = 0; nt < 4; ++nt)
#pragma unroll
            for (int j = 0; j < 4; ++j)
                D[(size_t)(w * 16 + g * 4 + j) * 64 + nt * 16 + m] = f2bf(acc[nt][j]);

        {
            const int r = t & 63, half = t >> 6;
            const int n0 = bi >> 2, q = bi & 3;
            const int pp = (2 * (n0 >> 3) + (q >> 1)) * GRID_P + 2 * (n0 & 7) + (q & 1);
            const float* posr = pos + (size_t)pp * C;
            float s = 0.f;
#pragma unroll 8
            for (int e = 0; e < 32; ++e) {
                const int c = half * 32 + e;
                s += (posr[c] + bp[c]) * ls[c * 68 + r];
            }
            red[r * 4 + half] = s;
        }
        __syncthreads();
        if (t < 64)
            pf[bi * 64 + t] = red[t * 4 + 0] + red[t * 4 + 1] + red[t * 4 + 2] + red[t * 4 + 3];
    } else if (bi < 340) {
        const int ti = bi - 256;
        const float* src;
        if      (ti < 64) src = f1 + (size_t)ti * 8192;
        else if (ti < 80) src = f2 + (size_t)(ti - 64) * 8192;
        else              src = f3 + (size_t)(ti - 80) * 8192;
        unsigned short* dst = fTL + (size_t)ti * 8192;
#pragma unroll
        for (int i = 0; i < 8; ++i) {
            const int fi = (t + 256 * i) * 4;
            const int c = fi >> 6, r = fi & 63;
            *(float4*)(ls + c * 68 + r) = *(const float4*)(src + fi);
        }
        __syncthreads();
        const int rr = t >> 2, seg = t & 3;
        unsigned int* d32 = (unsigned int*)(dst + rr * 128 + seg * 32);
#pragma unroll
        for (int ii = 0; ii < 16; ++ii) {
            const int c = seg * 32 + ii * 2;
            const unsigned int lo = f2bf(ls[c * 68 + rr]);
            const unsigned int hi = f2bf(ls[(c + 1) * 68 + rr]);
            d32[ii] = lo | (hi << 16);
        }
    } else if (bi < 425) {
        const int oi = bi - 340;
        const float* src;
        if      (oi < 64) src = o0 + (size_t)oi * 8192;
        else if (oi < 80) src = o1 + (size_t)(oi - 64) * 8192;
        else if (oi < 84) src = o2 + (size_t)(oi - 80) * 8192;
        else              src = o3 + (size_t)(oi - 84) * 8192;
        unsigned short* dst = oT + (size_t)oi * 8192;
#pragma unroll
        for (int i = 0; i < 8; ++i) {
            const int fi = (t + 256 * i) * 4;
            const int r = fi >> 7, c = fi & 127;
            *(float4*)(ls + r * 132 + c) = *(const float4*)(src + fi);
        }
        __syncthreads();
        const int cc = t >> 1, seg = t & 1;
        unsigned int* d32 = (unsigned int*)(dst + cc * 64 + seg * 32);
#pragma unroll
        for (int ii = 0; ii < 16; ++ii) {
            const int r = seg * 32 + ii * 2;
            const unsigned int lo = f2bf(ls[r * 132 + cc]);
            const unsigned int hi = f2bf(ls[(r + 1) * 132 + cc]);
            d32[ii] = lo | (hi << 16);
        }
    } else {
        const int j = bi - 425;
#pragma unroll
        for (int i = 0; i < 8; ++i) {
            const int fi = (t + 256 * i) * 4;
            const int c = fi >> 6, e = fi & 63;
            *(float4*)(ls + c * 68 + e) = *(const float4*)(Wh + (size_t)c * E + j * 64 + e);
        }
        __syncthreads();
        const int rr = t >> 2, seg = t & 3;
        unsigned int* d32 = (unsigned int*)(WhT + (size_t)(j * 64 + rr) * 128 + seg * 32);
#pragma unroll
        for (int ii = 0; ii < 16; ++ii) {
            const int c = seg * 32 + ii * 2;
            const unsigned int lo = f2bf(ls[c * 68 + rr]);
            const unsigned int hi = f2bf(ls[(c + 1) * 68 + rr]);
            d32[ii] = lo | (hi << 16);
        }
    }
}

// ---------------------------------------------------------------------------
// Fused level0+level1 (stage-free, R3 body, unchanged).
// NOTE (R5): this kernel is a pure function of (x, WfT, pf, oT, fT1) -> h2,
// so launching it twice is idempotent; the duplicate launch is an
// attribution probe (total-dur delta == one level01 execution).
// ---------------------------------------------------------------------------
__global__ __launch_bounds__(256, 3) void level01_fused(
    const float* __restrict__ x,              // (B,1,128,128)
    const unsigned short* __restrict__ WfT,   // 256 slices (64r x 64k)
    const float* __restrict__ pf,             // (256 x 64) fp32
    const unsigned short* __restrict__ oT,    // oT0 at slice n0, oT1 at 64+n1
    const unsigned short* __restrict__ fT1,   // 64 slices (64r x 128c)
    unsigned short* __restrict__ h2)          // (B,16,128) bf16
{
    __shared__ __align__(16) float          us1[4 * 16 * 68];   // 17408 B
    __shared__ __align__(16) unsigned short ps0[4 * 16 * 72];   //  9216 B
    __shared__ __align__(16) unsigned short ps1[16 * 72];       //  2304 B
    __shared__ __align__(16) unsigned short h1s[4 * 16 * 136];  // 17408 B
    // total 46336 B -> 3 blocks/CU

    const int bi = blockIdx.x;
    const int n1 = bi >> 5, btile = bi & 31;
    const int t = threadIdx.x, w = t >> 6, lane = t & 63;
    const int m = lane & 15, g = lane >> 4;
    const int bt = btile * 16;

    const int y1g = n1 >> 2, x1g = n1 & 3;
    const int Ry0 = y1g * 32, Rx0 = x1g * 32;
    const int n0 = (2 * y1g + (w >> 1)) * 8 + 2 * x1g + (w & 1);

    // ---- level0 pixel A-fragments: DIRECT global loads (batch = m) ----
    s16x8 a[4][2];
    {
        const int rbase = 16 * (w >> 1);
        const int cbase = 16 * (w & 1);
        const float* xb = x + (size_t)(bt + m) * (IMG * IMG);
#pragma unroll
        for (int q = 0; q < 4; ++q) {
            const int rq = rbase + 8 * (q >> 1) + g;
            const int cc = cbase + 8 * (q & 1);
#pragma unroll
            for (int kt = 0; kt < 2; ++kt) {
                const float* px = xb + (size_t)(Ry0 + rq + kt * 4) * IMG + Rx0 + cc;
                const float4 p0 = *(const float4*)px;
                const float4 p1 = *(const float4*)(px + 4);
                s16x8 fr;
                fr[0] = (short)f2bf(p0.x); fr[1] = (short)f2bf(p0.y);
                fr[2] = (short)f2bf(p0.z); fr[3] = (short)f2bf(p0.w);
                fr[4] = (short)f2bf(p1.x); fr[5] = (short)f2bf(p1.y);
                fr[6] = (short)f2bf(p1.z); fr[7] = (short)f2bf(p1.w);
                a[q][kt] = fr;
            }
        }
    }

    // ---- level0 u-phase (+pf init), all 4 quadrants in-wave ----
    f32x4 accu[4][4];
#pragma unroll
    for (int q = 0; q < 4; ++q) {
        const float* pfq = pf + (size_t)(n0 * 4 + q) * 64;
#pragma unroll
        for (int nt = 0; nt < 4; ++nt) {
            const float pv = pfq[nt * 16 + m];
            accu[q][nt] = (f32x4){pv, pv, pv, pv};
        }
    }
#pragma unroll
    for (int q = 0; q < 4; ++q) {
        const unsigned short* Wq = WfT + (size_t)(n0 * 4 + q) * 4096;
#pragma unroll
        for (int kt = 0; kt < 2; ++kt) {
            const int koff = kt * 32 + g * 8;
#pragma unroll
            for (int nt = 0; nt < 4; ++nt) {
                const s16x8 bfr = *(const s16x8*)(Wq + (size_t)(nt * 16 + m) * 64 + koff);
                accu[q][nt] = __builtin_amdgcn_mfma_f32_16x16x32_bf16(a[q][kt], bfr, accu[q][nt], 0, 0, 0);
            }
        }
    }

    // ---- level0 p-phase (regs) + wave-private ps roundtrip ----
    unsigned short* myps = ps0 + w * (16 * 72);
#pragma unroll
    for (int nt = 0; nt < 4; ++nt) {
        const f32x4 pr = accu[0][nt] * accu[1][nt] * accu[2][nt] * accu[3][nt];
#pragma unroll
        for (int j = 0; j < 4; ++j)
            myps[(g * 4 + j) * 72 + nt * 16 + m] = f2bf(pr[j]);
    }

    // ---- level0 o-phase (in-wave) -> h1 tile in wave-private LDS ----
    {
        s16x8 ap[2];
#pragma unroll
        for (int kt = 0; kt < 2; ++kt)
            ap[kt] = *(const s16x8*)(myps + m * 72 + kt * 32 + g * 8);
        const unsigned short* oTn = oT + (size_t)n0 * 8192;
        unsigned short* myh = h1s + w * (16 * 136);
#pragma unroll
        for (int ct = 0; ct < 8; ++ct) {
            f32x4 aco = (f32x4){0.f, 0.f, 0.f, 0.f};
#pragma unroll
            for (int kt = 0; kt < 2; ++kt) {
                const s16x8 bfr = *(const s16x8*)(oTn + (size_t)(ct * 16 + m) * 64 + kt * 32 + g * 8);
                aco = __builtin_amdgcn_mfma_f32_16x16x32_bf16(ap[kt], bfr, aco, 0, 0, 0);
            }
#pragma unroll
            for (int j = 0; j < 4; ++j)
                myh[(g * 4 + j) * 136 + ct * 16 + m] = f2bf(aco[j]);
        }
    }

    // ---- level1 u-phase: A = own h1 tile (wave-private, no barrier) ----
    {
        const unsigned short* myh = h1s + w * (16 * 136);
        const unsigned short* fq = fT1 + (size_t)(n1 * 4 + w) * 8192;
        f32x4 au[4];
#pragma unroll
        for (int nt = 0; nt < 4; ++nt) au[nt] = (f32x4){0.f, 0.f, 0.f, 0.f};
#pragma unroll
        for (int kt = 0; kt < 4; ++kt) {
            const int koff = kt * 32 + g * 8;
            const s16x8 afr = *(const s16x8*)(myh + m * 136 + koff);
#pragma unroll
            for (int nt = 0; nt < 4; ++nt) {
                const s16x8 bfr = *(const s16x8*)(fq + (size_t)(nt * 16 + m) * 128 + koff);
                au[nt] = __builtin_amdgcn_mfma_f32_16x16x32_bf16(afr, bfr, au[nt], 0, 0, 0);
            }
        }
#pragma unroll
        for (int nt = 0; nt < 4; ++nt)
#pragma unroll
            for (int j = 0; j < 4; ++j)
                us1[(w * 16 + g * 4 + j) * 68 + nt * 16 + m] = au[nt][j];
    }
    __syncthreads();

    // ---- level1 p-phase (block-wide) ----
    {
        const int pb = t >> 4, r0 = (t & 15) * 4;
        const f32x4 u0 = *(const f32x4*)(us1 + (0 * 16 + pb) * 68 + r0);
        const f32x4 u1 = *(const f32x4*)(us1 + (1 * 16 + pb) * 68 + r0);
        const f32x4 u2 = *(const f32x4*)(us1 + (2 * 16 + pb) * 68 + r0);
        const f32x4 u3 = *(const f32x4*)(us1 + (3 * 16 + pb) * 68 + r0);
        const f32x4 p = u0 * u1 * u2 * u3;
        uint2 v;
        v.x = (unsigned int)f2bf(p[0]) | ((unsigned int)f2bf(p[1]) << 16);
        v.y = (unsigned int)f2bf(p[2]) | ((unsigned int)f2bf(p[3]) << 16);
        *(uint2*)(ps1 + pb * 72 + r0) = v;
    }
    __syncthreads();

    // ---- level1 o-phase: wave handles ct = 2w, 2w+1 -> h2 ----
    {
        s16x8 ap[2];
#pragma unroll
        for (int kt = 0; kt < 2; ++kt)
            ap[kt] = *(const s16x8*)(ps1 + m * 72 + kt * 32 + g * 8);
        const unsigned short* oTn = oT + (size_t)(64 + n1) * 8192;
#pragma unroll
        for (int i = 0; i < 2; ++i) {
            const int ct = w * 2 + i;
            f32x4 aco = (f32x4){0.f, 0.f, 0.f, 0.f};
#pragma unroll
            for (int kt = 0; kt < 2; ++kt) {
                const s16x8 bfr = *(const s16x8*)(oTn + (size_t)(ct * 16 + m) * 64 + kt * 32 + g * 8);
                aco = __builtin_amdgcn_mfma_f32_16x16x32_bf16(ap[kt], bfr, aco, 0, 0, 0);
            }
#pragma unroll
            for (int j = 0; j < 4; ++j)
                h2[((size_t)(bt + g * 4 + j) * 16 + n1) * C + ct * 16 + m] = f2bf(aco[j]);
        }
    }
}

// ---------------------------------------------------------------------------
// Tail: level2 + level3 + LayerNorm + head + L2norm, block = 16 batches.
// (unchanged from R3)
// ---------------------------------------------------------------------------
__global__ __launch_bounds__(256, 1) void tail_kernel(
    const unsigned short* __restrict__ h2,    // (B,16,128) bf16
    const unsigned short* __restrict__ fT2,   // 16 slices (64 x 128)
    const unsigned short* __restrict__ oT2,   // 4 slices (128 x 64)
    const unsigned short* __restrict__ fT3,   // 4 slices (64 x 128)
    const unsigned short* __restrict__ oT3,   // 1 slice (128 x 64)
    const float* __restrict__ gamma, const float* __restrict__ beta,
    const unsigned short* __restrict__ WhT,   // (512 x 128) bf16
    const float* __restrict__ bh,             // (512)
    float* __restrict__ out)                  // (B,512) fp32
{
    __shared__ __align__(16) float          us3[4 * 16 * 68];
    __shared__ __align__(16) unsigned short ps2[4 * 16 * 72];
    __shared__ __align__(16) unsigned short ps3[16 * 72];
    __shared__ __align__(16) unsigned short h3s[16 * 4 * 136];
    __shared__ __align__(16) float          h4s[16 * 132];
    __shared__ __align__(16) unsigned short hns[16 * 136];
    __shared__ float red[16 * 4];

    const int bt = blockIdx.x * 16;
    const int t = threadIdx.x, w = t >> 6, lane = t & 63;
    const int m = lane & 15, g = lane >> 4;

    // ===== Level 2: wave w = node n2 =====
    {
        const int n2 = w;
        const int y1 = n2 >> 1, x1 = n2 & 1;

        s16x8 xa[4][4];    // [q][kt]
#pragma unroll
        for (int q = 0; q < 4; ++q) {
            const int pidx = (2 * y1 + (q >> 1)) * 4 + 2 * x1 + (q & 1);
            const unsigned short* xq = h2 + ((size_t)(bt + m) * 16 + pidx) * C;
#pragma unroll
            for (int kt = 0; kt < 4; ++kt)
                xa[q][kt] = *(const s16x8*)(xq + kt * 32 + g * 8);
        }

        f32x4 acc_u[4][4];
#pragma unroll
        for (int q = 0; q < 4; ++q)
#pragma unroll
            for (int nt = 0; nt < 4; ++nt) acc_u[q][nt] = (f32x4){0.f, 0.f, 0.f, 0.f};
#pragma unroll
        for (int q = 0; q < 4; ++q) {
            const unsigned short* fq = fT2 + (size_t)(n2 * 4 + q) * R * C;
#pragma unroll
            for (int kt = 0; kt < 4; ++kt) {
                const int koff = kt * 32 + g * 8;
#pragma unroll
                for (int nt = 0; nt < 4; ++nt) {
                    const s16x8 bfr = *(const s16x8*)(fq + (size_t)(nt * 16 + m) * C + koff);
                    acc_u[q][nt] = __builtin_amdgcn_mfma_f32_16x16x32_bf16(xa[q][kt], bfr, acc_u[q][nt], 0, 0, 0);
                }
            }
        }

        s16x8 ob[8][2];
        {
            const unsigned short* oTn = oT2 + (size_t)n2 * C * R;
#pragma unroll
            for (int ct = 0; ct < 8; ++ct)
#pragma unroll
                for (int kt = 0; kt < 2; ++kt)
                    ob[ct][kt] = *(const s16x8*)(oTn + (size_t)(ct * 16 + m) * R + kt * 32 + g * 8);
        }

        unsigned short* myps2 = ps2 + w * 16 * 72;
#pragma unroll
        for (int nt = 0; nt < 4; ++nt) {
            const f32x4 p = acc_u[0][nt] * acc_u[1][nt] * acc_u[2][nt] * acc_u[3][nt];
#pragma unroll
            for (int j = 0; j < 4; ++j)
                myps2[(g * 4 + j) * 72 + nt * 16 + m] = f2bf(p[j]);
        }
        f32x4 aco[8];
#pragma unroll
        for (int ct = 0; ct < 8; ++ct) aco[ct] = (f32x4){0.f, 0.f, 0.f, 0.f};
#pragma unroll
        for (int kt = 0; kt < 2; ++kt) {
            const int koff = kt * 32 + g * 8;
            const s16x8 av = *(const s16x8*)(myps2 + m * 72 + koff);
#pragma unroll
            for (int ct = 0; ct < 8; ++ct)
                aco[ct] = __builtin_amdgcn_mfma_f32_16x16x32_bf16(av, ob[ct][kt], aco[ct], 0, 0, 0);
        }
#pragma unroll
        for (int ct = 0; ct < 8; ++ct)
#pragma unroll
            for (int j = 0; j < 4; ++j)
                h3s[((g * 4 + j) * 4 + n2) * 136 + ct * 16 + m] = f2bf(aco[ct][j]);
    }
    __syncthreads();

    // ===== Level 3: wave w = quadrant q =====
    {
        const int q = w;
        s16x8 fb[4][4];   // [kt][nt]
        {
            const unsigned short* fq = fT3 + (size_t)q * R * C;
#pragma unroll
            for (int kt = 0; kt < 4; ++kt)
#pragma unroll
                for (int nt = 0; nt < 4; ++nt)
                    fb[kt][nt] = *(const s16x8*)(fq + (size_t)(nt * 16 + m) * C + kt * 32 + g * 8);
        }
        f32x4 acc_u[4];
#pragma unroll
        for (int nt = 0; nt < 4; ++nt) acc_u[nt] = (f32x4){0.f, 0.f, 0.f, 0.f};
#pragma unroll
        for (int kt = 0; kt < 4; ++kt) {
            const int koff = kt * 32 + g * 8;
            const s16x8 av = *(const s16x8*)(h3s + (m * 4 + q) * 136 + koff);
#pragma unroll
            for (int nt = 0; nt < 4; ++nt)
                acc_u[nt] = __builtin_amdgcn_mfma_f32_16x16x32_bf16(av, fb[kt][nt], acc_u[nt], 0, 0, 0);
        }
#pragma unroll
        for (int nt = 0; nt < 4; ++nt)
#pragma unroll
            for (int j = 0; j < 4; ++j)
                us3[(q * 16 + g * 4 + j) * 68 + nt * 16 + m] = acc_u[nt][j];
    }
    __syncthreads();
    {
        const int pb = t >> 4, r0 = (t & 15) * 4;
        const f32x4 u0 = *(const f32x4*)(us3 + (0 * 16 + pb) * 68 + r0);
        const f32x4 u1 = *(const f32x4*)(us3 + (1 * 16 + pb) * 68 + r0);
        const f32x4 u2 = *(const f32x4*)(us3 + (2 * 16 + pb) * 68 + r0);
        const f32x4 u3 = *(const f32x4*)(us3 + (3 * 16 + pb) * 68 + r0);
        const f32x4 p = u0 * u1 * u2 * u3;
        uint2 v;
        v.x = (unsigned int)f2bf(p[0]) | ((unsigned int)f2bf(p[1]) << 16);
        v.y = (unsigned int)f2bf(p[2]) | ((unsigned int)f2bf(p[3]) << 16);
        *(uint2*)(ps3 + pb * 72 + r0) = v;
    }
    __syncthreads();
    {
        s16x8 ap[2];
#pragma unroll
        for (int kt = 0; kt < 2; ++kt)
            ap[kt] = *(const s16x8*)(ps3 + m * 72 + kt * 32 + g * 8);
#pragma unroll
        for (int i = 0; i < 2; ++i) {
            f32x4 aco = (f32x4){0.f, 0.f, 0.f, 0.f};
            const int ct = w * 2 + i;
#pragma unroll
            for (int kt = 0; kt < 2; ++kt) {
                const s16x8 bfr = *(const s16x8*)(oT3 + (size_t)(ct * 16 + m) * R + kt * 32 + g * 8);
                aco = __builtin_amdgcn_mfma_f32_16x16x32_bf16(ap[kt], bfr, aco, 0, 0, 0);
            }
#pragma unroll
            for (int j = 0; j < 4; ++j)
                h4s[(g * 4 + j) * 132 + ct * 16 + m] = aco[j];
        }
    }
    __syncthreads();

    // ===== LayerNorm =====
    {
        const int rb = w * 4 + g;
        const int c0 = m * 8;
        const f32x4 v0 = *(const f32x4*)(h4s + rb * 132 + c0);
        const f32x4 v1 = *(const f32x4*)(h4s + rb * 132 + c0 + 4);
        float s  = v0[0] + v0[1] + v0[2] + v0[3] + v1[0] + v1[1] + v1[2] + v1[3];
        float ss = v0[0]*v0[0] + v0[1]*v0[1] + v0[2]*v0[2] + v0[3]*v0[3]
                 + v1[0]*v1[0] + v1[1]*v1[1] + v1[2]*v1[2] + v1[3]*v1[3];
#pragma unroll
        for (int off = 1; off < 16; off <<= 1) {
            s  += __shfl_xor(s, off);
            ss += __shfl_xor(ss, off);
        }
        const float mu   = s * (1.f / C);
        const float var  = ss * (1.f / C) - mu * mu;
        const float rstd = rsqrtf(var + 1e-5f);
        const f32x4 ga0 = *(const f32x4*)(gamma + c0);
        const f32x4 ga1 = *(const f32x4*)(gamma + c0 + 4);
        const f32x4 be0 = *(const f32x4*)(beta + c0);
        const f32x4 be1 = *(const f32x4*)(beta + c0 + 4);
        unsigned int o32[4];
        float hv[8];
#pragma unroll
        for (int k = 0; k < 4; ++k) hv[k]     = (v0[k] - mu) * rstd * ga0[k] + be0[k];
#pragma unroll
        for (int k = 0; k < 4; ++k) hv[4 + k] = (v1[k] - mu) * rstd * ga1[k] + be1[k];
#pragma unroll
        for (int k = 0; k < 4; ++k)
            o32[k] = (unsigned int)f2bf(hv[2*k]) | ((unsigned int)f2bf(hv[2*k+1]) << 16);
        *(uint4*)(hns + rb * 136 + c0) = *(uint4*)o32;
    }
    __syncthreads();

    // ===== Head GEMM + L2 norm =====
    {
        f32x4 acc[8];
#pragma unroll
        for (int nt = 0; nt < 8; ++nt) {
            const int e = w * 128 + nt * 16 + m;
            const float bv = bh[e];
            acc[nt] = (f32x4){bv, bv, bv, bv};
        }
#pragma unroll
        for (int kt = 0; kt < 4; ++kt) {
            const int koff = kt * 32 + g * 8;
            const s16x8 av = *(const s16x8*)(hns + m * 136 + koff);
#pragma unroll
            for (int nt = 0; nt < 8; ++nt) {
                const int e = w * 128 + nt * 16 + m;
                const s16x8 bfr = *(const s16x8*)(WhT + (size_t)e * 128 + koff);
                acc[nt] = __builtin_amdgcn_mfma_f32_16x16x32_bf16(av, bfr, acc[nt], 0, 0, 0);
            }
        }
        float sq[4];
#pragma unroll
        for (int j = 0; j < 4; ++j) {
            float s = 0.f;
#pragma unroll
            for (int nt = 0; nt < 8; ++nt) s += acc[nt][j] * acc[nt][j];
#pragma unroll
            for (int off = 1; off < 16; off <<= 1) s += __shfl_xor(s, off);
            sq[j] = s;
        }
        if (m == 0) {
#pragma unroll
            for (int j = 0; j < 4; ++j) red[(g * 4 + j) * 4 + w] = sq[j];
        }
        __syncthreads();
#pragma unroll
        for (int j = 0; j < 4; ++j) {
            const int row = g * 4 + j;
            const float tot = red[row * 4 + 0] + red[row * 4 + 1]
                            + red[row * 4 + 2] + red[row * 4 + 3];
            const float inv = 1.f / fmaxf(sqrtf(tot), 1e-12f);
#pragma unroll
            for (int nt = 0; nt < 8; ++nt) {
                const int e = w * 128 + nt * 16 + m;
                out[(size_t)(bt + row) * E + e] = acc[nt][j] * inv;
            }
        }
    }
}

// ---------------------------------------------------------------------------
extern "C" void kernel_launch(void* const* d_in, const int* in_sizes, int n_in,
                              void* d_out, int out_size, void* d_ws, size_t ws_size,
                              hipStream_t stream) {
    const float* x     = (const float*)d_in[0];
    const float* Wp    = (const float*)d_in[1];
    const float* bp    = (const float*)d_in[2];
    const float* pos   = (const float*)d_in[3];
    const float* gamma = (const float*)d_in[4];
    const float* beta  = (const float*)d_in[5];
    const float* Wh    = (const float*)d_in[6];
    const float* bh    = (const float*)d_in[7];
    const float* f0    = (const float*)d_in[8];
    const float* o0    = (const float*)d_in[9];
    const float* f1    = (const float*)d_in[10];
    const float* o1    = (const float*)d_in[11];
    const float* f2    = (const float*)d_in[12];
    const float* o2    = (const float*)d_in[13];
    const float* f3    = (const float*)d_in[14];
    const float* o3    = (const float*)d_in[15];
    float* out = (float*)d_out;

    // workspace layout (bf16 elements unless noted)
    unsigned short* h2  = (unsigned short*)d_ws;          // 1,048,576
    unsigned short* fTL = h2 + (size_t)1048576;           //   688,128 (84 slices)
    unsigned short* oT  = fTL + (size_t)688128;           //   696,320 (85 slices)
    unsigned short* WfT = oT + (size_t)696320;            // 1,048,576 (256 x 64x64)
    unsigned short* WhT = WfT + (size_t)1048576;          //    65,536
    float*          pff = (float*)(WhT + 65536);          //    16,384 fp32

    unsigned short* fT1 = fTL;
    unsigned short* fT2 = fTL + (size_t)64 * 8192;
    unsigned short* fT3 = fTL + (size_t)80 * 8192;
    unsigned short* oT2 = oT + (size_t)80 * 8192;
    unsigned short* oT3 = oT + (size_t)84 * 8192;

    prep_all_kernel<<<433, 256, 0, stream>>>(f0, f1, f2, f3, o0, o1, o2, o3,
                                             Wh, Wp, pos, bp,
                                             fTL, oT, WhT, WfT, pff);

    // R5 ATTRIBUTION PROBE: level01 launched twice (idempotent; pure
    // function (x,WfT,pf,oT,fT1)->h2). Total-dur delta vs R3 == one
    // level01 execution (warm). Output unchanged.
    level01_fused<<<16 * 32, 256, 0, stream>>>(x, WfT, pff, oT, fT1, h2);
    level01_fused<<<16 * 32, 256, 0, stream>>>(x, WfT, pff, oT, fT1, h2);

    tail_kernel<<<32, 256, 0, stream>>>(h2, fT2, oT2, fT3, oT3,
                                        gamma, beta, WhT, bh, out);
}

// Round 6
// 153.464 us; speedup vs baseline: 1.9775x; 1.1771x over previous
//
#include <hip/hip_runtime.h>
#include <hip/hip_bf16.h>

// Problem constants
#define BATCH     512
#define IMG       128
#define PS        8
#define GRID_P    16      // IMG/PS
#define NP        256     // GRID_P*GRID_P
#define C         128     // BOND_DIM
#define R         64      // CP_RANK
#define E         512     // EMBED_DIM

typedef float f32x4 __attribute__((ext_vector_type(4)));
typedef short s16x8 __attribute__((ext_vector_type(8)));

__device__ __forceinline__ unsigned short f2bf(float x) {
    unsigned int u = __float_as_uint(x);
    u += 0x7fffu + ((u >> 16) & 1u);          // RNE
    return (unsigned short)(u >> 16);
}

// ---------------------------------------------------------------------------
// prep_all (ONE launch, 433 blocks) -- unchanged.
// ---------------------------------------------------------------------------
__global__ __launch_bounds__(256) void prep_all_kernel(
    const float* __restrict__ f0, const float* __restrict__ f1,
    const float* __restrict__ f2, const float* __restrict__ f3,
    const float* __restrict__ o0, const float* __restrict__ o1,
    const float* __restrict__ o2, const float* __restrict__ o3,
    const float* __restrict__ Wh, const float* __restrict__ Wp,
    const float* __restrict__ pos, const float* __restrict__ bp,
    unsigned short* __restrict__ fTL, unsigned short* __restrict__ oT,
    unsigned short* __restrict__ WhT, unsigned short* __restrict__ WfT,
    float* __restrict__ pf)
{
    __shared__ float ls[128 * 68];    // 34.8 KB
    __shared__ float red[64 * 4];
    const int bi = blockIdx.x, t = threadIdx.x;

    if (bi < 256) {
        const float* src = f0 + (size_t)bi * 8192;
#pragma unroll
        for (int i = 0; i < 8; ++i) {
            const int fi = (t + 256 * i) * 4;
            const int c = fi >> 6, r = fi & 63;      // in[c][r]
            *(float4*)(ls + c * 68 + r) = *(const float4*)(src + fi);
        }
        __syncthreads();

        const int w = t >> 6, lane = t & 63;
        const int m = lane & 15, g = lane >> 4;

        f32x4 acc[4];
#pragma unroll
        for (int nt = 0; nt < 4; ++nt) acc[nt] = (f32x4){0.f, 0.f, 0.f, 0.f};
#pragma unroll
        for (int kt = 0; kt < 4; ++kt) {
            s16x8 afr;
#pragma unroll
            for (int e = 0; e < 8; ++e)
                afr[e] = (short)f2bf(ls[(kt * 32 + g * 8 + e) * 68 + w * 16 + m]);
#pragma unroll
            for (int nt = 0; nt < 4; ++nt) {
                const float* wr = Wp + (size_t)(nt * 16 + m) * 128 + kt * 32 + g * 8;
                const float4 b0 = *(const float4*)wr;
                const float4 b1 = *(const float4*)(wr + 4);
                s16x8 bfr;
                bfr[0] = (short)f2bf(b0.x); bfr[1] = (short)f2bf(b0.y);
                bfr[2] = (short)f2bf(b0.z); bfr[3] = (short)f2bf(b0.w);
                bfr[4] = (short)f2bf(b1.x); bfr[5] = (short)f2bf(b1.y);
                bfr[6] = (short)f2bf(b1.z); bfr[7] = (short)f2bf(b1.w);
                acc[nt] = __builtin_amdgcn_mfma_f32_16x16x32_bf16(afr, bfr, acc[nt], 0, 0, 0);
            }
        }
        unsigned short* D = WfT + (size_t)bi * 4096;
#pragma unroll
        for (int nt = 0; nt < 4; ++nt)
#pragma unroll
            for (int j = 0; j < 4; ++j)
                D[(size_t)(w * 16 + g * 4 + j) * 64 + nt * 16 + m] = f2bf(acc[nt][j]);

        {
            const int r = t & 63, half = t >> 6;
            const int n0 = bi >> 2, q = bi & 3;
            const int pp = (2 * (n0 >> 3) + (q >> 1)) * GRID_P + 2 * (n0 & 7) + (q & 1);
            const float* posr = pos + (size_t)pp * C;
            float s = 0.f;
#pragma unroll 8
            for (int e = 0; e < 32; ++e) {
                const int c = half * 32 + e;
                s += (posr[c] + bp[c]) * ls[c * 68 + r];
            }
            red[r * 4 + half] = s;
        }
        __syncthreads();
        if (t < 64)
            pf[bi * 64 + t] = red[t * 4 + 0] + red[t * 4 + 1] + red[t * 4 + 2] + red[t * 4 + 3];
    } else if (bi < 340) {
        const int ti = bi - 256;
        const float* src;
        if      (ti < 64) src = f1 + (size_t)ti * 8192;
        else if (ti < 80) src = f2 + (size_t)(ti - 64) * 8192;
        else              src = f3 + (size_t)(ti - 80) * 8192;
        unsigned short* dst = fTL + (size_t)ti * 8192;
#pragma unroll
        for (int i = 0; i < 8; ++i) {
            const int fi = (t + 256 * i) * 4;
            const int c = fi >> 6, r = fi & 63;
            *(float4*)(ls + c * 68 + r) = *(const float4*)(src + fi);
        }
        __syncthreads();
        const int rr = t >> 2, seg = t & 3;
        unsigned int* d32 = (unsigned int*)(dst + rr * 128 + seg * 32);
#pragma unroll
        for (int ii = 0; ii < 16; ++ii) {
            const int c = seg * 32 + ii * 2;
            const unsigned int lo = f2bf(ls[c * 68 + rr]);
            const unsigned int hi = f2bf(ls[(c + 1) * 68 + rr]);
            d32[ii] = lo | (hi << 16);
        }
    } else if (bi < 425) {
        const int oi = bi - 340;
        const float* src;
        if      (oi < 64) src = o0 + (size_t)oi * 8192;
        else if (oi < 80) src = o1 + (size_t)(oi - 64) * 8192;
        else if (oi < 84) src = o2 + (size_t)(oi - 80) * 8192;
        else              src = o3 + (size_t)(oi - 84) * 8192;
        unsigned short* dst = oT + (size_t)oi * 8192;
#pragma unroll
        for (int i = 0; i < 8; ++i) {
            const int fi = (t + 256 * i) * 4;
            const int r = fi >> 7, c = fi & 127;
            *(float4*)(ls + r * 132 + c) = *(const float4*)(src + fi);
        }
        __syncthreads();
        const int cc = t >> 1, seg = t & 1;
        unsigned int* d32 = (unsigned int*)(dst + cc * 64 + seg * 32);
#pragma unroll
        for (int ii = 0; ii < 16; ++ii) {
            const int r = seg * 32 + ii * 2;
            const unsigned int lo = f2bf(ls[r * 132 + cc]);
            const unsigned int hi = f2bf(ls[(r + 1) * 132 + cc]);
            d32[ii] = lo | (hi << 16);
        }
    } else {
        const int j = bi - 425;
#pragma unroll
        for (int i = 0; i < 8; ++i) {
            const int fi = (t + 256 * i) * 4;
            const int c = fi >> 6, e = fi & 63;
            *(float4*)(ls + c * 68 + e) = *(const float4*)(Wh + (size_t)c * E + j * 64 + e);
        }
        __syncthreads();
        const int rr = t >> 2, seg = t & 3;
        unsigned int* d32 = (unsigned int*)(WhT + (size_t)(j * 64 + rr) * 128 + seg * 32);
#pragma unroll
        for (int ii = 0; ii < 16; ++ii) {
            const int c = seg * 32 + ii * 2;
            const unsigned int lo = f2bf(ls[c * 68 + rr]);
            const unsigned int hi = f2bf(ls[(c + 1) * 68 + rr]);
            d32[ii] = lo | (hi << 16);
        }
    }
}

// ---------------------------------------------------------------------------
// Fused level0+level1 (stage-free body, unchanged) + R6 XCD-AWARE SWIZZLE.
// Old mapping: n1 = bi>>5, btile = bi&31 -> consecutive blocks (same n1,
// sharing the same ~0.5 MB weight working set) round-robin across 8 XCDs
// with non-coherent L2s, so every XCD pulls the whole ~4.5 MB weight set
// through L3/HBM and the 32x per-n1 re-reads (~130 MB) never L2-hit.
// New mapping: XCD x (= bi%8 under round-robin dispatch) gets exactly
// n1 in {2x, 2x+1}; its working set (~1 MB) L2-resides and the other 31
// btiles hit local L2. Bijective relabeling (512 = 8*2*32): output
// identical, absmax 0.0.
// ---------------------------------------------------------------------------
__global__ __launch_bounds__(256, 3) void level01_fused(
    const float* __restrict__ x,              // (B,1,128,128)
    const unsigned short* __restrict__ WfT,   // 256 slices (64r x 64k)
    const float* __restrict__ pf,             // (256 x 64) fp32
    const unsigned short* __restrict__ oT,    // oT0 at slice n0, oT1 at 64+n1
    const unsigned short* __restrict__ fT1,   // 64 slices (64r x 128c)
    unsigned short* __restrict__ h2)          // (B,16,128) bf16
{
    __shared__ __align__(16) float          us1[4 * 16 * 68];   // 17408 B
    __shared__ __align__(16) unsigned short ps0[4 * 16 * 72];   //  9216 B
    __shared__ __align__(16) unsigned short ps1[16 * 72];       //  2304 B
    __shared__ __align__(16) unsigned short h1s[4 * 16 * 136];  // 17408 B
    // total 46336 B -> 3 blocks/CU

    const int bi = blockIdx.x;
    // ---- R6: XCD-aware (n1, btile) assignment ----
    const int n1 = ((bi & 7) << 1) | ((bi >> 3) & 1);
    const int btile = bi >> 4;
    const int t = threadIdx.x, w = t >> 6, lane = t & 63;
    const int m = lane & 15, g = lane >> 4;
    const int bt = btile * 16;

    const int y1g = n1 >> 2, x1g = n1 & 3;
    const int Ry0 = y1g * 32, Rx0 = x1g * 32;
    const int n0 = (2 * y1g + (w >> 1)) * 8 + 2 * x1g + (w & 1);

    // ---- level0 pixel A-fragments: DIRECT global loads (batch = m) ----
    s16x8 a[4][2];
    {
        const int rbase = 16 * (w >> 1);
        const int cbase = 16 * (w & 1);
        const float* xb = x + (size_t)(bt + m) * (IMG * IMG);
#pragma unroll
        for (int q = 0; q < 4; ++q) {
            const int rq = rbase + 8 * (q >> 1) + g;
            const int cc = cbase + 8 * (q & 1);
#pragma unroll
            for (int kt = 0; kt < 2; ++kt) {
                const float* px = xb + (size_t)(Ry0 + rq + kt * 4) * IMG + Rx0 + cc;
                const float4 p0 = *(const float4*)px;
                const float4 p1 = *(const float4*)(px + 4);
                s16x8 fr;
                fr[0] = (short)f2bf(p0.x); fr[1] = (short)f2bf(p0.y);
                fr[2] = (short)f2bf(p0.z); fr[3] = (short)f2bf(p0.w);
                fr[4] = (short)f2bf(p1.x); fr[5] = (short)f2bf(p1.y);
                fr[6] = (short)f2bf(p1.z); fr[7] = (short)f2bf(p1.w);
                a[q][kt] = fr;
            }
        }
    }

    // ---- level0 u-phase (+pf init), all 4 quadrants in-wave ----
    f32x4 accu[4][4];
#pragma unroll
    for (int q = 0; q < 4; ++q) {
        const float* pfq = pf + (size_t)(n0 * 4 + q) * 64;
#pragma unroll
        for (int nt = 0; nt < 4; ++nt) {
            const float pv = pfq[nt * 16 + m];
            accu[q][nt] = (f32x4){pv, pv, pv, pv};
        }
    }
#pragma unroll
    for (int q = 0; q < 4; ++q) {
        const unsigned short* Wq = WfT + (size_t)(n0 * 4 + q) * 4096;
#pragma unroll
        for (int kt = 0; kt < 2; ++kt) {
            const int koff = kt * 32 + g * 8;
#pragma unroll
            for (int nt = 0; nt < 4; ++nt) {
                const s16x8 bfr = *(const s16x8*)(Wq + (size_t)(nt * 16 + m) * 64 + koff);
                accu[q][nt] = __builtin_amdgcn_mfma_f32_16x16x32_bf16(a[q][kt], bfr, accu[q][nt], 0, 0, 0);
            }
        }
    }

    // ---- level0 p-phase (regs) + wave-private ps roundtrip ----
    unsigned short* myps = ps0 + w * (16 * 72);
#pragma unroll
    for (int nt = 0; nt < 4; ++nt) {
        const f32x4 pr = accu[0][nt] * accu[1][nt] * accu[2][nt] * accu[3][nt];
#pragma unroll
        for (int j = 0; j < 4; ++j)
            myps[(g * 4 + j) * 72 + nt * 16 + m] = f2bf(pr[j]);
    }

    // ---- level0 o-phase (in-wave) -> h1 tile in wave-private LDS ----
    {
        s16x8 ap[2];
#pragma unroll
        for (int kt = 0; kt < 2; ++kt)
            ap[kt] = *(const s16x8*)(myps + m * 72 + kt * 32 + g * 8);
        const unsigned short* oTn = oT + (size_t)n0 * 8192;
        unsigned short* myh = h1s + w * (16 * 136);
#pragma unroll
        for (int ct = 0; ct < 8; ++ct) {
            f32x4 aco = (f32x4){0.f, 0.f, 0.f, 0.f};
#pragma unroll
            for (int kt = 0; kt < 2; ++kt) {
                const s16x8 bfr = *(const s16x8*)(oTn + (size_t)(ct * 16 + m) * 64 + kt * 32 + g * 8);
                aco = __builtin_amdgcn_mfma_f32_16x16x32_bf16(ap[kt], bfr, aco, 0, 0, 0);
            }
#pragma unroll
            for (int j = 0; j < 4; ++j)
                myh[(g * 4 + j) * 136 + ct * 16 + m] = f2bf(aco[j]);
        }
    }

    // ---- level1 u-phase: A = own h1 tile (wave-private, no barrier) ----
    {
        const unsigned short* myh = h1s + w * (16 * 136);
        const unsigned short* fq = fT1 + (size_t)(n1 * 4 + w) * 8192;
        f32x4 au[4];
#pragma unroll
        for (int nt = 0; nt < 4; ++nt) au[nt] = (f32x4){0.f, 0.f, 0.f, 0.f};
#pragma unroll
        for (int kt = 0; kt < 4; ++kt) {
            const int koff = kt * 32 + g * 8;
            const s16x8 afr = *(const s16x8*)(myh + m * 136 + koff);
#pragma unroll
            for (int nt = 0; nt < 4; ++nt) {
                const s16x8 bfr = *(const s16x8*)(fq + (size_t)(nt * 16 + m) * 128 + koff);
                au[nt] = __builtin_amdgcn_mfma_f32_16x16x32_bf16(afr, bfr, au[nt], 0, 0, 0);
            }
        }
#pragma unroll
        for (int nt = 0; nt < 4; ++nt)
#pragma unroll
            for (int j = 0; j < 4; ++j)
                us1[(w * 16 + g * 4 + j) * 68 + nt * 16 + m] = au[nt][j];
    }
    __syncthreads();

    // ---- level1 p-phase (block-wide) ----
    {
        const int pb = t >> 4, r0 = (t & 15) * 4;
        const f32x4 u0 = *(const f32x4*)(us1 + (0 * 16 + pb) * 68 + r0);
        const f32x4 u1 = *(const f32x4*)(us1 + (1 * 16 + pb) * 68 + r0);
        const f32x4 u2 = *(const f32x4*)(us1 + (2 * 16 + pb) * 68 + r0);
        const f32x4 u3 = *(const f32x4*)(us1 + (3 * 16 + pb) * 68 + r0);
        const f32x4 p = u0 * u1 * u2 * u3;
        uint2 v;
        v.x = (unsigned int)f2bf(p[0]) | ((unsigned int)f2bf(p[1]) << 16);
        v.y = (unsigned int)f2bf(p[2]) | ((unsigned int)f2bf(p[3]) << 16);
        *(uint2*)(ps1 + pb * 72 + r0) = v;
    }
    __syncthreads();

    // ---- level1 o-phase: wave handles ct = 2w, 2w+1 -> h2 ----
    {
        s16x8 ap[2];
#pragma unroll
        for (int kt = 0; kt < 2; ++kt)
            ap[kt] = *(const s16x8*)(ps1 + m * 72 + kt * 32 + g * 8);
        const unsigned short* oTn = oT + (size_t)(64 + n1) * 8192;
#pragma unroll
        for (int i = 0; i < 2; ++i) {
            const int ct = w * 2 + i;
            f32x4 aco = (f32x4){0.f, 0.f, 0.f, 0.f};
#pragma unroll
            for (int kt = 0; kt < 2; ++kt) {
                const s16x8 bfr = *(const s16x8*)(oTn + (size_t)(ct * 16 + m) * 64 + kt * 32 + g * 8);
                aco = __builtin_amdgcn_mfma_f32_16x16x32_bf16(ap[kt], bfr, aco, 0, 0, 0);
            }
#pragma unroll
            for (int j = 0; j < 4; ++j)
                h2[((size_t)(bt + g * 4 + j) * 16 + n1) * C + ct * 16 + m] = f2bf(aco[j]);
        }
    }
}

// ---------------------------------------------------------------------------
// Tail: level2 + level3 + LayerNorm + head + L2norm, block = 16 batches.
// (unchanged)
// ---------------------------------------------------------------------------
__global__ __launch_bounds__(256, 1) void tail_kernel(
    const unsigned short* __restrict__ h2,    // (B,16,128) bf16
    const unsigned short* __restrict__ fT2,   // 16 slices (64 x 128)
    const unsigned short* __restrict__ oT2,   // 4 slices (128 x 64)
    const unsigned short* __restrict__ fT3,   // 4 slices (64 x 128)
    const unsigned short* __restrict__ oT3,   // 1 slice (128 x 64)
    const float* __restrict__ gamma, const float* __restrict__ beta,
    const unsigned short* __restrict__ WhT,   // (512 x 128) bf16
    const float* __restrict__ bh,             // (512)
    float* __restrict__ out)                  // (B,512) fp32
{
    __shared__ __align__(16) float          us3[4 * 16 * 68];
    __shared__ __align__(16) unsigned short ps2[4 * 16 * 72];
    __shared__ __align__(16) unsigned short ps3[16 * 72];
    __shared__ __align__(16) unsigned short h3s[16 * 4 * 136];
    __shared__ __align__(16) float          h4s[16 * 132];
    __shared__ __align__(16) unsigned short hns[16 * 136];
    __shared__ float red[16 * 4];

    const int bt = blockIdx.x * 16;
    const int t = threadIdx.x, w = t >> 6, lane = t & 63;
    const int m = lane & 15, g = lane >> 4;

    // ===== Level 2: wave w = node n2 =====
    {
        const int n2 = w;
        const int y1 = n2 >> 1, x1 = n2 & 1;

        s16x8 xa[4][4];    // [q][kt]
#pragma unroll
        for (int q = 0; q < 4; ++q) {
            const int pidx = (2 * y1 + (q >> 1)) * 4 + 2 * x1 + (q & 1);
            const unsigned short* xq = h2 + ((size_t)(bt + m) * 16 + pidx) * C;
#pragma unroll
            for (int kt = 0; kt < 4; ++kt)
                xa[q][kt] = *(const s16x8*)(xq + kt * 32 + g * 8);
        }

        f32x4 acc_u[4][4];
#pragma unroll
        for (int q = 0; q < 4; ++q)
#pragma unroll
            for (int nt = 0; nt < 4; ++nt) acc_u[q][nt] = (f32x4){0.f, 0.f, 0.f, 0.f};
#pragma unroll
        for (int q = 0; q < 4; ++q) {
            const unsigned short* fq = fT2 + (size_t)(n2 * 4 + q) * R * C;
#pragma unroll
            for (int kt = 0; kt < 4; ++kt) {
                const int koff = kt * 32 + g * 8;
#pragma unroll
                for (int nt = 0; nt < 4; ++nt) {
                    const s16x8 bfr = *(const s16x8*)(fq + (size_t)(nt * 16 + m) * C + koff);
                    acc_u[q][nt] = __builtin_amdgcn_mfma_f32_16x16x32_bf16(xa[q][kt], bfr, acc_u[q][nt], 0, 0, 0);
                }
            }
        }

        s16x8 ob[8][2];
        {
            const unsigned short* oTn = oT2 + (size_t)n2 * C * R;
#pragma unroll
            for (int ct = 0; ct < 8; ++ct)
#pragma unroll
                for (int kt = 0; kt < 2; ++kt)
                    ob[ct][kt] = *(const s16x8*)(oTn + (size_t)(ct * 16 + m) * R + kt * 32 + g * 8);
        }

        unsigned short* myps2 = ps2 + w * 16 * 72;
#pragma unroll
        for (int nt = 0; nt < 4; ++nt) {
            const f32x4 p = acc_u[0][nt] * acc_u[1][nt] * acc_u[2][nt] * acc_u[3][nt];
#pragma unroll
            for (int j = 0; j < 4; ++j)
                myps2[(g * 4 + j) * 72 + nt * 16 + m] = f2bf(p[j]);
        }
        f32x4 aco[8];
#pragma unroll
        for (int ct = 0; ct < 8; ++ct) aco[ct] = (f32x4){0.f, 0.f, 0.f, 0.f};
#pragma unroll
        for (int kt = 0; kt < 2; ++kt) {
            const int koff = kt * 32 + g * 8;
            const s16x8 av = *(const s16x8*)(myps2 + m * 72 + koff);
#pragma unroll
            for (int ct = 0; ct < 8; ++ct)
                aco[ct] = __builtin_amdgcn_mfma_f32_16x16x32_bf16(av, ob[ct][kt], aco[ct], 0, 0, 0);
        }
#pragma unroll
        for (int ct = 0; ct < 8; ++ct)
#pragma unroll
            for (int j = 0; j < 4; ++j)
                h3s[((g * 4 + j) * 4 + n2) * 136 + ct * 16 + m] = f2bf(aco[ct][j]);
    }
    __syncthreads();

    // ===== Level 3: wave w = quadrant q =====
    {
        const int q = w;
        s16x8 fb[4][4];   // [kt][nt]
        {
            const unsigned short* fq = fT3 + (size_t)q * R * C;
#pragma unroll
            for (int kt = 0; kt < 4; ++kt)
#pragma unroll
                for (int nt = 0; nt < 4; ++nt)
                    fb[kt][nt] = *(const s16x8*)(fq + (size_t)(nt * 16 + m) * C + kt * 32 + g * 8);
        }
        f32x4 acc_u[4];
#pragma unroll
        for (int nt = 0; nt < 4; ++nt) acc_u[nt] = (f32x4){0.f, 0.f, 0.f, 0.f};
#pragma unroll
        for (int kt = 0; kt < 4; ++kt) {
            const int koff = kt * 32 + g * 8;
            const s16x8 av = *(const s16x8*)(h3s + (m * 4 + q) * 136 + koff);
#pragma unroll
            for (int nt = 0; nt < 4; ++nt)
                acc_u[nt] = __builtin_amdgcn_mfma_f32_16x16x32_bf16(av, fb[kt][nt], acc_u[nt], 0, 0, 0);
        }
#pragma unroll
        for (int nt = 0; nt < 4; ++nt)
#pragma unroll
            for (int j = 0; j < 4; ++j)
                us3[(q * 16 + g * 4 + j) * 68 + nt * 16 + m] = acc_u[nt][j];
    }
    __syncthreads();
    {
        const int pb = t >> 4, r0 = (t & 15) * 4;
        const f32x4 u0 = *(const f32x4*)(us3 + (0 * 16 + pb) * 68 + r0);
        const f32x4 u1 = *(const f32x4*)(us3 + (1 * 16 + pb) * 68 + r0);
        const f32x4 u2 = *(const f32x4*)(us3 + (2 * 16 + pb) * 68 + r0);
        const f32x4 u3 = *(const f32x4*)(us3 + (3 * 16 + pb) * 68 + r0);
        const f32x4 p = u0 * u1 * u2 * u3;
        uint2 v;
        v.x = (unsigned int)f2bf(p[0]) | ((unsigned int)f2bf(p[1]) << 16);
        v.y = (unsigned int)f2bf(p[2]) | ((unsigned int)f2bf(p[3]) << 16);
        *(uint2*)(ps3 + pb * 72 + r0) = v;
    }
    __syncthreads();
    {
        s16x8 ap[2];
#pragma unroll
        for (int kt = 0; kt < 2; ++kt)
            ap[kt] = *(const s16x8*)(ps3 + m * 72 + kt * 32 + g * 8);
#pragma unroll
        for (int i = 0; i < 2; ++i) {
            f32x4 aco = (f32x4){0.f, 0.f, 0.f, 0.f};
            const int ct = w * 2 + i;
#pragma unroll
            for (int kt = 0; kt < 2; ++kt) {
                const s16x8 bfr = *(const s16x8*)(oT3 + (size_t)(ct * 16 + m) * R + kt * 32 + g * 8);
                aco = __builtin_amdgcn_mfma_f32_16x16x32_bf16(ap[kt], bfr, aco, 0, 0, 0);
            }
#pragma unroll
            for (int j = 0; j < 4; ++j)
                h4s[(g * 4 + j) * 132 + ct * 16 + m] = aco[j];
        }
    }
    __syncthreads();

    // ===== LayerNorm =====
    {
        const int rb = w * 4 + g;
        const int c0 = m * 8;
        const f32x4 v0 = *(const f32x4*)(h4s + rb * 132 + c0);
        const f32x4 v1 = *(const f32x4*)(h4s + rb * 132 + c0 + 4);
        float s  = v0[0] + v0[1] + v0[2] + v0[3] + v1[0] + v1[1] + v1[2] + v1[3];
        float ss = v0[0]*v0[0] + v0[1]*v0[1] + v0[2]*v0[2] + v0[3]*v0[3]
                 + v1[0]*v1[0] + v1[1]*v1[1] + v1[2]*v1[2] + v1[3]*v1[3];
#pragma unroll
        for (int off = 1; off < 16; off <<= 1) {
            s  += __shfl_xor(s, off);
            ss += __shfl_xor(ss, off);
        }
        const float mu   = s * (1.f / C);
        const float var  = ss * (1.f / C) - mu * mu;
        const float rstd = rsqrtf(var + 1e-5f);
        const f32x4 ga0 = *(const f32x4*)(gamma + c0);
        const f32x4 ga1 = *(const f32x4*)(gamma + c0 + 4);
        const f32x4 be0 = *(const f32x4*)(beta + c0);
        const f32x4 be1 = *(const f32x4*)(beta + c0 + 4);
        unsigned int o32[4];
        float hv[8];
#pragma unroll
        for (int k = 0; k < 4; ++k) hv[k]     = (v0[k] - mu) * rstd * ga0[k] + be0[k];
#pragma unroll
        for (int k = 0; k < 4; ++k) hv[4 + k] = (v1[k] - mu) * rstd * ga1[k] + be1[k];
#pragma unroll
        for (int k = 0; k < 4; ++k)
            o32[k] = (unsigned int)f2bf(hv[2*k]) | ((unsigned int)f2bf(hv[2*k+1]) << 16);
        *(uint4*)(hns + rb * 136 + c0) = *(uint4*)o32;
    }
    __syncthreads();

    // ===== Head GEMM + L2 norm =====
    {
        f32x4 acc[8];
#pragma unroll
        for (int nt = 0; nt < 8; ++nt) {
            const int e = w * 128 + nt * 16 + m;
            const float bv = bh[e];
            acc[nt] = (f32x4){bv, bv, bv, bv};
        }
#pragma unroll
        for (int kt = 0; kt < 4; ++kt) {
            const int koff = kt * 32 + g * 8;
            const s16x8 av = *(const s16x8*)(hns + m * 136 + koff);
#pragma unroll
            for (int nt = 0; nt < 8; ++nt) {
                const int e = w * 128 + nt * 16 + m;
                const s16x8 bfr = *(const s16x8*)(WhT + (size_t)e * 128 + koff);
                acc[nt] = __builtin_amdgcn_mfma_f32_16x16x32_bf16(av, bfr, acc[nt], 0, 0, 0);
            }
        }
        float sq[4];
#pragma unroll
        for (int j = 0; j < 4; ++j) {
            float s = 0.f;
#pragma unroll
            for (int nt = 0; nt < 8; ++nt) s += acc[nt][j] * acc[nt][j];
#pragma unroll
            for (int off = 1; off < 16; off <<= 1) s += __shfl_xor(s, off);
            sq[j] = s;
        }
        if (m == 0) {
#pragma unroll
            for (int j = 0; j < 4; ++j) red[(g * 4 + j) * 4 + w] = sq[j];
        }
        __syncthreads();
#pragma unroll
        for (int j = 0; j < 4; ++j) {
            const int row = g * 4 + j;
            const float tot = red[row * 4 + 0] + red[row * 4 + 1]
                            + red[row * 4 + 2] + red[row * 4 + 3];
            const float inv = 1.f / fmaxf(sqrtf(tot), 1e-12f);
#pragma unroll
            for (int nt = 0; nt < 8; ++nt) {
                const int e = w * 128 + nt * 16 + m;
                out[(size_t)(bt + row) * E + e] = acc[nt][j] * inv;
            }
        }
    }
}

// ---------------------------------------------------------------------------
extern "C" void kernel_launch(void* const* d_in, const int* in_sizes, int n_in,
                              void* d_out, int out_size, void* d_ws, size_t ws_size,
                              hipStream_t stream) {
    const float* x     = (const float*)d_in[0];
    const float* Wp    = (const float*)d_in[1];
    const float* bp    = (const float*)d_in[2];
    const float* pos   = (const float*)d_in[3];
    const float* gamma = (const float*)d_in[4];
    const float* beta  = (const float*)d_in[5];
    const float* Wh    = (const float*)d_in[6];
    const float* bh    = (const float*)d_in[7];
    const float* f0    = (const float*)d_in[8];
    const float* o0    = (const float*)d_in[9];
    const float* f1    = (const float*)d_in[10];
    const float* o1    = (const float*)d_in[11];
    const float* f2    = (const float*)d_in[12];
    const float* o2    = (const float*)d_in[13];
    const float* f3    = (const float*)d_in[14];
    const float* o3    = (const float*)d_in[15];
    float* out = (float*)d_out;

    // workspace layout (bf16 elements unless noted)
    unsigned short* h2  = (unsigned short*)d_ws;          // 1,048,576
    unsigned short* fTL = h2 + (size_t)1048576;           //   688,128 (84 slices)
    unsigned short* oT  = fTL + (size_t)688128;           //   696,320 (85 slices)
    unsigned short* WfT = oT + (size_t)696320;            // 1,048,576 (256 x 64x64)
    unsigned short* WhT = WfT + (size_t)1048576;          //    65,536
    float*          pff = (float*)(WhT + 65536);          //    16,384 fp32

    unsigned short* fT1 = fTL;
    unsigned short* fT2 = fTL + (size_t)64 * 8192;
    unsigned short* fT3 = fTL + (size_t)80 * 8192;
    unsigned short* oT2 = oT + (size_t)80 * 8192;
    unsigned short* oT3 = oT + (size_t)84 * 8192;

    prep_all_kernel<<<433, 256, 0, stream>>>(f0, f1, f2, f3, o0, o1, o2, o3,
                                             Wh, Wp, pos, bp,
                                             fTL, oT, WhT, WfT, pff);

    level01_fused<<<16 * 32, 256, 0, stream>>>(x, WfT, pff, oT, fT1, h2);

    tail_kernel<<<32, 256, 0, stream>>>(h2, fT2, oT2, fT3, oT3,
                                        gamma, beta, WhT, bh, out);
}

// Round 7
// 145.403 us; speedup vs baseline: 2.0871x; 1.0554x over previous
//
#include <hip/hip_runtime.h>
#include <hip/hip_bf16.h>

// Problem constants
#define BATCH     512
#define IMG       128
#define PS        8
#define GRID_P    16      // IMG/PS
#define NP        256     // GRID_P*GRID_P
#define C         128     // BOND_DIM
#define R         64      // CP_RANK
#define E         512     // EMBED_DIM

typedef float f32x4 __attribute__((ext_vector_type(4)));
typedef short s16x8 __attribute__((ext_vector_type(8)));

__device__ __forceinline__ unsigned short f2bf(float x) {
    unsigned int u = __float_as_uint(x);
    u += 0x7fffu + ((u >> 16) & 1u);          // RNE
    return (unsigned short)(u >> 16);
}

// ---------------------------------------------------------------------------
// R7 LAYOUTS (level01 weights only; tail arrays unchanged):
//  WfT slice (4096 sh):  [grp=kt*4+nt][lane][8]  -- u-phase B-fragments
//  fT1 slice (8192 sh):  [grp=kt*4+nt][lane][8]  -- level1 u-phase (kt 0..3)
//  oT  slice (8192 sh):  [grp=ct*2+kt][lane][8]  -- o-phase (slices 0..79)
// Every MFMA B-fragment load becomes base + grp*512sh + lane*8sh: one
// contiguous 1KB wave read = 16 cache lines (vs 64 scattered before).
// Pure permutation, identical f2bf conversions -> bit-identical output.
// ---------------------------------------------------------------------------

// ---------------------------------------------------------------------------
// prep_all (ONE launch, 433 blocks):
//   bi <256 : WfT+pf for level-0 slice (n0,q)=bi  (WfT in fragment-major)
//   bi 256..339 : f1/f2/f3 -> fTL   (slices <64 fragment-major, rest old)
//   bi 340..424 : o -> oT           (slices <80 fragment-major, rest old)
//   bi 425..432 : Wh -> WhT (old layout)
// ---------------------------------------------------------------------------
__global__ __launch_bounds__(256) void prep_all_kernel(
    const float* __restrict__ f0, const float* __restrict__ f1,
    const float* __restrict__ f2, const float* __restrict__ f3,
    const float* __restrict__ o0, const float* __restrict__ o1,
    const float* __restrict__ o2, const float* __restrict__ o3,
    const float* __restrict__ Wh, const float* __restrict__ Wp,
    const float* __restrict__ pos, const float* __restrict__ bp,
    unsigned short* __restrict__ fTL, unsigned short* __restrict__ oT,
    unsigned short* __restrict__ WhT, unsigned short* __restrict__ WfT,
    float* __restrict__ pf)
{
    __shared__ float ls[128 * 68];    // 34.8 KB
    __shared__ float red[64 * 4];
    const int bi = blockIdx.x, t = threadIdx.x;

    if (bi < 256) {
        const float* src = f0 + (size_t)bi * 8192;
#pragma unroll
        for (int i = 0; i < 8; ++i) {
            const int fi = (t + 256 * i) * 4;
            const int c = fi >> 6, r = fi & 63;      // in[c][r]
            *(float4*)(ls + c * 68 + r) = *(const float4*)(src + fi);
        }
        __syncthreads();

        const int w = t >> 6, lane = t & 63;
        const int m = lane & 15, g = lane >> 4;

        f32x4 acc[4];
#pragma unroll
        for (int nt = 0; nt < 4; ++nt) acc[nt] = (f32x4){0.f, 0.f, 0.f, 0.f};
#pragma unroll
        for (int kt = 0; kt < 4; ++kt) {
            s16x8 afr;
#pragma unroll
            for (int e = 0; e < 8; ++e)
                afr[e] = (short)f2bf(ls[(kt * 32 + g * 8 + e) * 68 + w * 16 + m]);
#pragma unroll
            for (int nt = 0; nt < 4; ++nt) {
                const float* wr = Wp + (size_t)(nt * 16 + m) * 128 + kt * 32 + g * 8;
                const float4 b0 = *(const float4*)wr;
                const float4 b1 = *(const float4*)(wr + 4);
                s16x8 bfr;
                bfr[0] = (short)f2bf(b0.x); bfr[1] = (short)f2bf(b0.y);
                bfr[2] = (short)f2bf(b0.z); bfr[3] = (short)f2bf(b0.w);
                bfr[4] = (short)f2bf(b1.x); bfr[5] = (short)f2bf(b1.y);
                bfr[6] = (short)f2bf(b1.z); bfr[7] = (short)f2bf(b1.w);
                acc[nt] = __builtin_amdgcn_mfma_f32_16x16x32_bf16(afr, bfr, acc[nt], 0, 0, 0);
            }
        }
        // WfT store, fragment-major: element (P = w*16+g*4+j, Q = nt*16+m)
        // -> N = (((Q>>5)*4 + w)*64 + ((Q>>3)&3)*16 + (g*4+j))*8 + (Q&7)
        unsigned short* D = WfT + (size_t)bi * 4096;
#pragma unroll
        for (int nt = 0; nt < 4; ++nt)
#pragma unroll
            for (int j = 0; j < 4; ++j) {
                const int Q = nt * 16 + m;
                const int N = (((Q >> 5) * 4 + w) * 64 + ((Q >> 3) & 3) * 16 + (g * 4 + j)) * 8 + (Q & 7);
                D[N] = f2bf(acc[nt][j]);
            }

        {
            const int r = t & 63, half = t >> 6;
            const int n0 = bi >> 2, q = bi & 3;
            const int pp = (2 * (n0 >> 3) + (q >> 1)) * GRID_P + 2 * (n0 & 7) + (q & 1);
            const float* posr = pos + (size_t)pp * C;
            float s = 0.f;
#pragma unroll 8
            for (int e = 0; e < 32; ++e) {
                const int c = half * 32 + e;
                s += (posr[c] + bp[c]) * ls[c * 68 + r];
            }
            red[r * 4 + half] = s;
        }
        __syncthreads();
        if (t < 64)
            pf[bi * 64 + t] = red[t * 4 + 0] + red[t * 4 + 1] + red[t * 4 + 2] + red[t * 4 + 3];
    } else if (bi < 340) {
        const int ti = bi - 256;
        const float* src;
        if      (ti < 64) src = f1 + (size_t)ti * 8192;
        else if (ti < 80) src = f2 + (size_t)(ti - 64) * 8192;
        else              src = f3 + (size_t)(ti - 80) * 8192;
        unsigned short* dst = fTL + (size_t)ti * 8192;
#pragma unroll
        for (int i = 0; i < 8; ++i) {
            const int fi = (t + 256 * i) * 4;
            const int c = fi >> 6, r = fi & 63;
            *(float4*)(ls + c * 68 + r) = *(const float4*)(src + fi);
        }
        __syncthreads();
        if (ti < 64) {
            // fT1: fragment-major [grp=kt*4+nt][lane][8]; coalesced 16B stores
#pragma unroll
            for (int k = 0; k < 4; ++k) {
                const int unit = t + 256 * k;      // 0..1023
                const int grp = unit >> 6, lp = unit & 63;
                const int kt = grp >> 2, nt = grp & 3;
                const int mp = lp & 15, gp = lp >> 4;
                s16x8 v;
#pragma unroll
                for (int e = 0; e < 8; ++e)
                    v[e] = (short)f2bf(ls[(kt * 32 + gp * 8 + e) * 68 + nt * 16 + mp]);
                *(s16x8*)(dst + (size_t)(grp * 64 + lp) * 8) = v;
            }
        } else {
            // fT2/fT3: old layout
            const int rr = t >> 2, seg = t & 3;
            unsigned int* d32 = (unsigned int*)(dst + rr * 128 + seg * 32);
#pragma unroll
            for (int ii = 0; ii < 16; ++ii) {
                const int c = seg * 32 + ii * 2;
                const unsigned int lo = f2bf(ls[c * 68 + rr]);
                const unsigned int hi = f2bf(ls[(c + 1) * 68 + rr]);
                d32[ii] = lo | (hi << 16);
            }
        }
    } else if (bi < 425) {
        const int oi = bi - 340;
        const float* src;
        if      (oi < 64) src = o0 + (size_t)oi * 8192;
        else if (oi < 80) src = o1 + (size_t)(oi - 64) * 8192;
        else if (oi < 84) src = o2 + (size_t)(oi - 80) * 8192;
        else              src = o3 + (size_t)(oi - 84) * 8192;
        unsigned short* dst = oT + (size_t)oi * 8192;
#pragma unroll
        for (int i = 0; i < 8; ++i) {
            const int fi = (t + 256 * i) * 4;
            const int r = fi >> 7, c = fi & 127;
            *(float4*)(ls + r * 132 + c) = *(const float4*)(src + fi);
        }
        __syncthreads();
        if (oi < 80) {
            // oT0/oT1: fragment-major [grp=ct*2+kt][lane][8]; coalesced stores
#pragma unroll
            for (int k = 0; k < 4; ++k) {
                const int unit = t + 256 * k;      // 0..1023
                const int grp = unit >> 6, lp = unit & 63;
                const int ct = grp >> 1, kt = grp & 1;
                const int mp = lp & 15, gp = lp >> 4;
                s16x8 v;
#pragma unroll
                for (int e = 0; e < 8; ++e)
                    v[e] = (short)f2bf(ls[(kt * 32 + gp * 8 + e) * 132 + ct * 16 + mp]);
                *(s16x8*)(dst + (size_t)(grp * 64 + lp) * 8) = v;
            }
        } else {
            // oT2/oT3: old layout
            const int cc = t >> 1, seg = t & 1;
            unsigned int* d32 = (unsigned int*)(dst + cc * 64 + seg * 32);
#pragma unroll
            for (int ii = 0; ii < 16; ++ii) {
                const int r = seg * 32 + ii * 2;
                const unsigned int lo = f2bf(ls[r * 132 + cc]);
                const unsigned int hi = f2bf(ls[(r + 1) * 132 + cc]);
                d32[ii] = lo | (hi << 16);
            }
        }
    } else {
        const int j = bi - 425;
#pragma unroll
        for (int i = 0; i < 8; ++i) {
            const int fi = (t + 256 * i) * 4;
            const int c = fi >> 6, e = fi & 63;
            *(float4*)(ls + c * 68 + e) = *(const float4*)(Wh + (size_t)c * E + j * 64 + e);
        }
        __syncthreads();
        const int rr = t >> 2, seg = t & 3;
        unsigned int* d32 = (unsigned int*)(WhT + (size_t)(j * 64 + rr) * 128 + seg * 32);
#pragma unroll
        for (int ii = 0; ii < 16; ++ii) {
            const int c = seg * 32 + ii * 2;
            const unsigned int lo = f2bf(ls[c * 68 + rr]);
            const unsigned int hi = f2bf(ls[(c + 1) * 68 + rr]);
            d32[ii] = lo | (hi << 16);
        }
    }
}

// ---------------------------------------------------------------------------
// Fused level0+level1 (stage-free) with FRAGMENT-MAJOR weight reads:
// every B-fragment load = base + grp*512sh + lane*8sh -> contiguous 1KB
// wave read (16 lines vs 64 scattered). XCD-aware (n1,btile) kept from R6.
// ---------------------------------------------------------------------------
__global__ __launch_bounds__(256, 3) void level01_fused(
    const float* __restrict__ x,              // (B,1,128,128)
    const unsigned short* __restrict__ WfT,   // 256 slices, fragment-major
    const float* __restrict__ pf,             // (256 x 64) fp32
    const unsigned short* __restrict__ oT,    // slices 0..79 fragment-major
    const unsigned short* __restrict__ fT1,   // 64 slices, fragment-major
    unsigned short* __restrict__ h2)          // (B,16,128) bf16
{
    __shared__ __align__(16) float          us1[4 * 16 * 68];   // 17408 B
    __shared__ __align__(16) unsigned short ps0[4 * 16 * 72];   //  9216 B
    __shared__ __align__(16) unsigned short ps1[16 * 72];       //  2304 B
    __shared__ __align__(16) unsigned short h1s[4 * 16 * 136];  // 17408 B
    // total 46336 B -> 3 blocks/CU

    const int bi = blockIdx.x;
    const int n1 = ((bi & 7) << 1) | ((bi >> 3) & 1);     // R6 XCD swizzle
    const int btile = bi >> 4;
    const int t = threadIdx.x, w = t >> 6, lane = t & 63;
    const int m = lane & 15, g = lane >> 4;
    const int bt = btile * 16;

    const int y1g = n1 >> 2, x1g = n1 & 3;
    const int Ry0 = y1g * 32, Rx0 = x1g * 32;
    const int n0 = (2 * y1g + (w >> 1)) * 8 + 2 * x1g + (w & 1);

    // ---- level0 pixel A-fragments: DIRECT global loads (batch = m) ----
    s16x8 a[4][2];
    {
        const int rbase = 16 * (w >> 1);
        const int cbase = 16 * (w & 1);
        const float* xb = x + (size_t)(bt + m) * (IMG * IMG);
#pragma unroll
        for (int q = 0; q < 4; ++q) {
            const int rq = rbase + 8 * (q >> 1) + g;
            const int cc = cbase + 8 * (q & 1);
#pragma unroll
            for (int kt = 0; kt < 2; ++kt) {
                const float* px = xb + (size_t)(Ry0 + rq + kt * 4) * IMG + Rx0 + cc;
                const float4 p0 = *(const float4*)px;
                const float4 p1 = *(const float4*)(px + 4);
                s16x8 fr;
                fr[0] = (short)f2bf(p0.x); fr[1] = (short)f2bf(p0.y);
                fr[2] = (short)f2bf(p0.z); fr[3] = (short)f2bf(p0.w);
                fr[4] = (short)f2bf(p1.x); fr[5] = (short)f2bf(p1.y);
                fr[6] = (short)f2bf(p1.z); fr[7] = (short)f2bf(p1.w);
                a[q][kt] = fr;
            }
        }
    }

    // ---- level0 u-phase (+pf init), all 4 quadrants in-wave ----
    f32x4 accu[4][4];
#pragma unroll
    for (int q = 0; q < 4; ++q) {
        const float* pfq = pf + (size_t)(n0 * 4 + q) * 64;
#pragma unroll
        for (int nt = 0; nt < 4; ++nt) {
            const float pv = pfq[nt * 16 + m];
            accu[q][nt] = (f32x4){pv, pv, pv, pv};
        }
    }
#pragma unroll
    for (int q = 0; q < 4; ++q) {
        const unsigned short* Wq = WfT + (size_t)(n0 * 4 + q) * 4096;
#pragma unroll
        for (int kt = 0; kt < 2; ++kt) {
#pragma unroll
            for (int nt = 0; nt < 4; ++nt) {
                const s16x8 bfr = *(const s16x8*)(Wq + (size_t)((kt * 4 + nt) * 64 + lane) * 8);
                accu[q][nt] = __builtin_amdgcn_mfma_f32_16x16x32_bf16(a[q][kt], bfr, accu[q][nt], 0, 0, 0);
            }
        }
    }

    // ---- level0 p-phase (regs) + wave-private ps roundtrip ----
    unsigned short* myps = ps0 + w * (16 * 72);
#pragma unroll
    for (int nt = 0; nt < 4; ++nt) {
        const f32x4 pr = accu[0][nt] * accu[1][nt] * accu[2][nt] * accu[3][nt];
#pragma unroll
        for (int j = 0; j < 4; ++j)
            myps[(g * 4 + j) * 72 + nt * 16 + m] = f2bf(pr[j]);
    }

    // ---- level0 o-phase (in-wave) -> h1 tile in wave-private LDS ----
    {
        s16x8 ap[2];
#pragma unroll
        for (int kt = 0; kt < 2; ++kt)
            ap[kt] = *(const s16x8*)(myps + m * 72 + kt * 32 + g * 8);
        const unsigned short* oTn = oT + (size_t)n0 * 8192;
        unsigned short* myh = h1s + w * (16 * 136);
#pragma unroll
        for (int ct = 0; ct < 8; ++ct) {
            f32x4 aco = (f32x4){0.f, 0.f, 0.f, 0.f};
#pragma unroll
            for (int kt = 0; kt < 2; ++kt) {
                const s16x8 bfr = *(const s16x8*)(oTn + (size_t)((ct * 2 + kt) * 64 + lane) * 8);
                aco = __builtin_amdgcn_mfma_f32_16x16x32_bf16(ap[kt], bfr, aco, 0, 0, 0);
            }
#pragma unroll
            for (int j = 0; j < 4; ++j)
                myh[(g * 4 + j) * 136 + ct * 16 + m] = f2bf(aco[j]);
        }
    }

    // ---- level1 u-phase: A = own h1 tile (wave-private, no barrier) ----
    {
        const unsigned short* myh = h1s + w * (16 * 136);
        const unsigned short* fq = fT1 + (size_t)(n1 * 4 + w) * 8192;
        f32x4 au[4];
#pragma unroll
        for (int nt = 0; nt < 4; ++nt) au[nt] = (f32x4){0.f, 0.f, 0.f, 0.f};
#pragma unroll
        for (int kt = 0; kt < 4; ++kt) {
            const int koff = kt * 32 + g * 8;
            const s16x8 afr = *(const s16x8*)(myh + m * 136 + koff);
#pragma unroll
            for (int nt = 0; nt < 4; ++nt) {
                const s16x8 bfr = *(const s16x8*)(fq + (size_t)((kt * 4 + nt) * 64 + lane) * 8);
                au[nt] = __builtin_amdgcn_mfma_f32_16x16x32_bf16(afr, bfr, au[nt], 0, 0, 0);
            }
        }
#pragma unroll
        for (int nt = 0; nt < 4; ++nt)
#pragma unroll
            for (int j = 0; j < 4; ++j)
                us1[(w * 16 + g * 4 + j) * 68 + nt * 16 + m] = au[nt][j];
    }
    __syncthreads();

    // ---- level1 p-phase (block-wide) ----
    {
        const int pb = t >> 4, r0 = (t & 15) * 4;
        const f32x4 u0 = *(const f32x4*)(us1 + (0 * 16 + pb) * 68 + r0);
        const f32x4 u1 = *(const f32x4*)(us1 + (1 * 16 + pb) * 68 + r0);
        const f32x4 u2 = *(const f32x4*)(us1 + (2 * 16 + pb) * 68 + r0);
        const f32x4 u3 = *(const f32x4*)(us1 + (3 * 16 + pb) * 68 + r0);
        const f32x4 p = u0 * u1 * u2 * u3;
        uint2 v;
        v.x = (unsigned int)f2bf(p[0]) | ((unsigned int)f2bf(p[1]) << 16);
        v.y = (unsigned int)f2bf(p[2]) | ((unsigned int)f2bf(p[3]) << 16);
        *(uint2*)(ps1 + pb * 72 + r0) = v;
    }
    __syncthreads();

    // ---- level1 o-phase: wave handles ct = 2w, 2w+1 -> h2 ----
    {
        s16x8 ap[2];
#pragma unroll
        for (int kt = 0; kt < 2; ++kt)
            ap[kt] = *(const s16x8*)(ps1 + m * 72 + kt * 32 + g * 8);
        const unsigned short* oTn = oT + (size_t)(64 + n1) * 8192;
#pragma unroll
        for (int i = 0; i < 2; ++i) {
            const int ct = w * 2 + i;
            f32x4 aco = (f32x4){0.f, 0.f, 0.f, 0.f};
#pragma unroll
            for (int kt = 0; kt < 2; ++kt) {
                const s16x8 bfr = *(const s16x8*)(oTn + (size_t)((ct * 2 + kt) * 64 + lane) * 8);
                aco = __builtin_amdgcn_mfma_f32_16x16x32_bf16(ap[kt], bfr, aco, 0, 0, 0);
            }
#pragma unroll
            for (int j = 0; j < 4; ++j)
                h2[((size_t)(bt + g * 4 + j) * 16 + n1) * C + ct * 16 + m] = f2bf(aco[j]);
        }
    }
}

// ---------------------------------------------------------------------------
// Tail: level2 + level3 + LayerNorm + head + L2norm, block = 16 batches.
// (unchanged; uses old-layout fT2/oT2/fT3/oT3/WhT)
// ---------------------------------------------------------------------------
__global__ __launch_bounds__(256, 1) void tail_kernel(
    const unsigned short* __restrict__ h2,    // (B,16,128) bf16
    const unsigned short* __restrict__ fT2,   // 16 slices (64 x 128)
    const unsigned short* __restrict__ oT2,   // 4 slices (128 x 64)
    const unsigned short* __restrict__ fT3,   // 4 slices (64 x 128)
    const unsigned short* __restrict__ oT3,   // 1 slice (128 x 64)
    const float* __restrict__ gamma, const float* __restrict__ beta,
    const unsigned short* __restrict__ WhT,   // (512 x 128) bf16
    const float* __restrict__ bh,             // (512)
    float* __restrict__ out)                  // (B,512) fp32
{
    __shared__ __align__(16) float          us3[4 * 16 * 68];
    __shared__ __align__(16) unsigned short ps2[4 * 16 * 72];
    __shared__ __align__(16) unsigned short ps3[16 * 72];
    __shared__ __align__(16) unsigned short h3s[16 * 4 * 136];
    __shared__ __align__(16) float          h4s[16 * 132];
    __shared__ __align__(16) unsigned short hns[16 * 136];
    __shared__ float red[16 * 4];

    const int bt = blockIdx.x * 16;
    const int t = threadIdx.x, w = t >> 6, lane = t & 63;
    const int m = lane & 15, g = lane >> 4;

    // ===== Level 2: wave w = node n2 =====
    {
        const int n2 = w;
        const int y1 = n2 >> 1, x1 = n2 & 1;

        s16x8 xa[4][4];    // [q][kt]
#pragma unroll
        for (int q = 0; q < 4; ++q) {
            const int pidx = (2 * y1 + (q >> 1)) * 4 + 2 * x1 + (q & 1);
            const unsigned short* xq = h2 + ((size_t)(bt + m) * 16 + pidx) * C;
#pragma unroll
            for (int kt = 0; kt < 4; ++kt)
                xa[q][kt] = *(const s16x8*)(xq + kt * 32 + g * 8);
        }

        f32x4 acc_u[4][4];
#pragma unroll
        for (int q = 0; q < 4; ++q)
#pragma unroll
            for (int nt = 0; nt < 4; ++nt) acc_u[q][nt] = (f32x4){0.f, 0.f, 0.f, 0.f};
#pragma unroll
        for (int q = 0; q < 4; ++q) {
            const unsigned short* fq = fT2 + (size_t)(n2 * 4 + q) * R * C;
#pragma unroll
            for (int kt = 0; kt < 4; ++kt) {
                const int koff = kt * 32 + g * 8;
#pragma unroll
                for (int nt = 0; nt < 4; ++nt) {
                    const s16x8 bfr = *(const s16x8*)(fq + (size_t)(nt * 16 + m) * C + koff);
                    acc_u[q][nt] = __builtin_amdgcn_mfma_f32_16x16x32_bf16(xa[q][kt], bfr, acc_u[q][nt], 0, 0, 0);
                }
            }
        }

        s16x8 ob[8][2];
        {
            const unsigned short* oTn = oT2 + (size_t)n2 * C * R;
#pragma unroll
            for (int ct = 0; ct < 8; ++ct)
#pragma unroll
                for (int kt = 0; kt < 2; ++kt)
                    ob[ct][kt] = *(const s16x8*)(oTn + (size_t)(ct * 16 + m) * R + kt * 32 + g * 8);
        }

        unsigned short* myps2 = ps2 + w * 16 * 72;
#pragma unroll
        for (int nt = 0; nt < 4; ++nt) {
            const f32x4 p = acc_u[0][nt] * acc_u[1][nt] * acc_u[2][nt] * acc_u[3][nt];
#pragma unroll
            for (int j = 0; j < 4; ++j)
                myps2[(g * 4 + j) * 72 + nt * 16 + m] = f2bf(p[j]);
        }
        f32x4 aco[8];
#pragma unroll
        for (int ct = 0; ct < 8; ++ct) aco[ct] = (f32x4){0.f, 0.f, 0.f, 0.f};
#pragma unroll
        for (int kt = 0; kt < 2; ++kt) {
            const int koff = kt * 32 + g * 8;
            const s16x8 av = *(const s16x8*)(myps2 + m * 72 + koff);
#pragma unroll
            for (int ct = 0; ct < 8; ++ct)
                aco[ct] = __builtin_amdgcn_mfma_f32_16x16x32_bf16(av, ob[ct][kt], aco[ct], 0, 0, 0);
        }
#pragma unroll
        for (int ct = 0; ct < 8; ++ct)
#pragma unroll
            for (int j = 0; j < 4; ++j)
                h3s[((g * 4 + j) * 4 + n2) * 136 + ct * 16 + m] = f2bf(aco[ct][j]);
    }
    __syncthreads();

    // ===== Level 3: wave w = quadrant q =====
    {
        const int q = w;
        s16x8 fb[4][4];   // [kt][nt]
        {
            const unsigned short* fq = fT3 + (size_t)q * R * C;
#pragma unroll
            for (int kt = 0; kt < 4; ++kt)
#pragma unroll
                for (int nt = 0; nt < 4; ++nt)
                    fb[kt][nt] = *(const s16x8*)(fq + (size_t)(nt * 16 + m) * C + kt * 32 + g * 8);
        }
        f32x4 acc_u[4];
#pragma unroll
        for (int nt = 0; nt < 4; ++nt) acc_u[nt] = (f32x4){0.f, 0.f, 0.f, 0.f};
#pragma unroll
        for (int kt = 0; kt < 4; ++kt) {
            const int koff = kt * 32 + g * 8;
            const s16x8 av = *(const s16x8*)(h3s + (m * 4 + q) * 136 + koff);
#pragma unroll
            for (int nt = 0; nt < 4; ++nt)
                acc_u[nt] = __builtin_amdgcn_mfma_f32_16x16x32_bf16(av, fb[kt][nt], acc_u[nt], 0, 0, 0);
        }
#pragma unroll
        for (int nt = 0; nt < 4; ++nt)
#pragma unroll
            for (int j = 0; j < 4; ++j)
                us3[(q * 16 + g * 4 + j) * 68 + nt * 16 + m] = acc_u[nt][j];
    }
    __syncthreads();
    {
        const int pb = t >> 4, r0 = (t & 15) * 4;
        const f32x4 u0 = *(const f32x4*)(us3 + (0 * 16 + pb) * 68 + r0);
        const f32x4 u1 = *(const f32x4*)(us3 + (1 * 16 + pb) * 68 + r0);
        const f32x4 u2 = *(const f32x4*)(us3 + (2 * 16 + pb) * 68 + r0);
        const f32x4 u3 = *(const f32x4*)(us3 + (3 * 16 + pb) * 68 + r0);
        const f32x4 p = u0 * u1 * u2 * u3;
        uint2 v;
        v.x = (unsigned int)f2bf(p[0]) | ((unsigned int)f2bf(p[1]) << 16);
        v.y = (unsigned int)f2bf(p[2]) | ((unsigned int)f2bf(p[3]) << 16);
        *(uint2*)(ps3 + pb * 72 + r0) = v;
    }
    __syncthreads();
    {
        s16x8 ap[2];
#pragma unroll
        for (int kt = 0; kt < 2; ++kt)
            ap[kt] = *(const s16x8*)(ps3 + m * 72 + kt * 32 + g * 8);
#pragma unroll
        for (int i = 0; i < 2; ++i) {
            f32x4 aco = (f32x4){0.f, 0.f, 0.f, 0.f};
            const int ct = w * 2 + i;
#pragma unroll
            for (int kt = 0; kt < 2; ++kt) {
                const s16x8 bfr = *(const s16x8*)(oT3 + (size_t)(ct * 16 + m) * R + kt * 32 + g * 8);
                aco = __builtin_amdgcn_mfma_f32_16x16x32_bf16(ap[kt], bfr, aco, 0, 0, 0);
            }
#pragma unroll
            for (int j = 0; j < 4; ++j)
                h4s[(g * 4 + j) * 132 + ct * 16 + m] = aco[j];
        }
    }
    __syncthreads();

    // ===== LayerNorm =====
    {
        const int rb = w * 4 + g;
        const int c0 = m * 8;
        const f32x4 v0 = *(const f32x4*)(h4s + rb * 132 + c0);
        const f32x4 v1 = *(const f32x4*)(h4s + rb * 132 + c0 + 4);
        float s  = v0[0] + v0[1] + v0[2] + v0[3] + v1[0] + v1[1] + v1[2] + v1[3];
        float ss = v0[0]*v0[0] + v0[1]*v0[1] + v0[2]*v0[2] + v0[3]*v0[3]
                 + v1[0]*v1[0] + v1[1]*v1[1] + v1[2]*v1[2] + v1[3]*v1[3];
#pragma unroll
        for (int off = 1; off < 16; off <<= 1) {
            s  += __shfl_xor(s, off);
            ss += __shfl_xor(ss, off);
        }
        const float mu   = s * (1.f / C);
        const float var  = ss * (1.f / C) - mu * mu;
        const float rstd = rsqrtf(var + 1e-5f);
        const f32x4 ga0 = *(const f32x4*)(gamma + c0);
        const f32x4 ga1 = *(const f32x4*)(gamma + c0 + 4);
        const f32x4 be0 = *(const f32x4*)(beta + c0);
        const f32x4 be1 = *(const f32x4*)(beta + c0 + 4);
        unsigned int o32[4];
        float hv[8];
#pragma unroll
        for (int k = 0; k < 4; ++k) hv[k]     = (v0[k] - mu) * rstd * ga0[k] + be0[k];
#pragma unroll
        for (int k = 0; k < 4; ++k) hv[4 + k] = (v1[k] - mu) * rstd * ga1[k] + be1[k];
#pragma unroll
        for (int k = 0; k < 4; ++k)
            o32[k] = (unsigned int)f2bf(hv[2*k]) | ((unsigned int)f2bf(hv[2*k+1]) << 16);
        *(uint4*)(hns + rb * 136 + c0) = *(uint4*)o32;
    }
    __syncthreads();

    // ===== Head GEMM + L2 norm =====
    {
        f32x4 acc[8];
#pragma unroll
        for (int nt = 0; nt < 8; ++nt) {
            const int e = w * 128 + nt * 16 + m;
            const float bv = bh[e];
            acc[nt] = (f32x4){bv, bv, bv, bv};
        }
#pragma unroll
        for (int kt = 0; kt < 4; ++kt) {
            const int koff = kt * 32 + g * 8;
            const s16x8 av = *(const s16x8*)(hns + m * 136 + koff);
#pragma unroll
            for (int nt = 0; nt < 8; ++nt) {
                const int e = w * 128 + nt * 16 + m;
                const s16x8 bfr = *(const s16x8*)(WhT + (size_t)e * 128 + koff);
                acc[nt] = __builtin_amdgcn_mfma_f32_16x16x32_bf16(av, bfr, acc[nt], 0, 0, 0);
            }
        }
        float sq[4];
#pragma unroll
        for (int j = 0; j < 4; ++j) {
            float s = 0.f;
#pragma unroll
            for (int nt = 0; nt < 8; ++nt) s += acc[nt][j] * acc[nt][j];
#pragma unroll
            for (int off = 1; off < 16; off <<= 1) s += __shfl_xor(s, off);
            sq[j] = s;
        }
        if (m == 0) {
#pragma unroll
            for (int j = 0; j < 4; ++j) red[(g * 4 + j) * 4 + w] = sq[j];
        }
        __syncthreads();
#pragma unroll
        for (int j = 0; j < 4; ++j) {
            const int row = g * 4 + j;
            const float tot = red[row * 4 + 0] + red[row * 4 + 1]
                            + red[row * 4 + 2] + red[row * 4 + 3];
            const float inv = 1.f / fmaxf(sqrtf(tot), 1e-12f);
#pragma unroll
            for (int nt = 0; nt < 8; ++nt) {
                const int e = w * 128 + nt * 16 + m;
                out[(size_t)(bt + row) * E + e] = acc[nt][j] * inv;
            }
        }
    }
}

// ---------------------------------------------------------------------------
extern "C" void kernel_launch(void* const* d_in, const int* in_sizes, int n_in,
                              void* d_out, int out_size, void* d_ws, size_t ws_size,
                              hipStream_t stream) {
    const float* x     = (const float*)d_in[0];
    const float* Wp    = (const float*)d_in[1];
    const float* bp    = (const float*)d_in[2];
    const float* pos   = (const float*)d_in[3];
    const float* gamma = (const float*)d_in[4];
    const float* beta  = (const float*)d_in[5];
    const float* Wh    = (const float*)d_in[6];
    const float* bh    = (const float*)d_in[7];
    const float* f0    = (const float*)d_in[8];
    const float* o0    = (const float*)d_in[9];
    const float* f1    = (const float*)d_in[10];
    const float* o1    = (const float*)d_in[11];
    const float* f2    = (const float*)d_in[12];
    const float* o2    = (const float*)d_in[13];
    const float* f3    = (const float*)d_in[14];
    const float* o3    = (const float*)d_in[15];
    float* out = (float*)d_out;

    // workspace layout (bf16 elements unless noted)
    unsigned short* h2  = (unsigned short*)d_ws;          // 1,048,576
    unsigned short* fTL = h2 + (size_t)1048576;           //   688,128 (84 slices)
    unsigned short* oT  = fTL + (size_t)688128;           //   696,320 (85 slices)
    unsigned short* WfT = oT + (size_t)696320;            // 1,048,576 (256 x 64x64)
    unsigned short* WhT = WfT + (size_t)1048576;          //    65,536
    float*          pff = (float*)(WhT + 65536);          //    16,384 fp32

    unsigned short* fT1 = fTL;
    unsigned short* fT2 = fTL + (size_t)64 * 8192;
    unsigned short* fT3 = fTL + (size_t)80 * 8192;
    unsigned short* oT2 = oT + (size_t)80 * 8192;
    unsigned short* oT3 = oT + (size_t)84 * 8192;

    prep_all_kernel<<<433, 256, 0, stream>>>(f0, f1, f2, f3, o0, o1, o2, o3,
                                             Wh, Wp, pos, bp,
                                             fTL, oT, WhT, WfT, pff);

    level01_fused<<<16 * 32, 256, 0, stream>>>(x, WfT, pff, oT, fT1, h2);

    tail_kernel<<<32, 256, 0, stream>>>(h2, fT2, oT2, fT3, oT3,
                                        gamma, beta, WhT, bh, out);
}

// Round 8
// 134.190 us; speedup vs baseline: 2.2615x; 1.0836x over previous
//
#include <hip/hip_runtime.h>
#include <hip/hip_bf16.h>

// Problem constants
#define BATCH     512
#define IMG       128
#define PS        8
#define GRID_P    16      // IMG/PS
#define NP        256     // GRID_P*GRID_P
#define C         128     // BOND_DIM
#define R         64      // CP_RANK
#define E         512     // EMBED_DIM

typedef float f32x4 __attribute__((ext_vector_type(4)));
typedef short s16x8 __attribute__((ext_vector_type(8)));

__device__ __forceinline__ unsigned short f2bf(float x) {
    unsigned int u = __float_as_uint(x);
    u += 0x7fffu + ((u >> 16) & 1u);          // RNE
    return (unsigned short)(u >> 16);
}

// ---------------------------------------------------------------------------
// R8 LAYOUTS (validated TCP line-request model, ~1 line/cy/TCP):
//  ALL f-slices  (fT1,fT2,fT3): [grp=kt*4+nt][lane][8]   (8192 sh/slice)
//  ALL o-slices  (oT0..oT3):    [grp=ct*2+kt][lane][8]   (8192 sh/slice)
//  WfT slice:                   [grp=kt*4+nt][lane][8]   (4096 sh/slice)
//  WhT:                         [grp=w*32+kt*8+nt][lane][8]
//  h2:                          [n1][batch][c]  (tail reads 32 vs 64 lines)
// Every B-fragment load = one contiguous 1KB wave read = 16 lines.
// level01 x: coalesced pixs LDS staging (8 lines/instr vs 64 direct).
// Pure permutations, identical f2bf conversions -> bit-identical output.
// ---------------------------------------------------------------------------

// ---------------------------------------------------------------------------
// prep_all (ONE launch, 433 blocks)
// ---------------------------------------------------------------------------
__global__ __launch_bounds__(256) void prep_all_kernel(
    const float* __restrict__ f0, const float* __restrict__ f1,
    const float* __restrict__ f2, const float* __restrict__ f3,
    const float* __restrict__ o0, const float* __restrict__ o1,
    const float* __restrict__ o2, const float* __restrict__ o3,
    const float* __restrict__ Wh, const float* __restrict__ Wp,
    const float* __restrict__ pos, const float* __restrict__ bp,
    unsigned short* __restrict__ fTL, unsigned short* __restrict__ oT,
    unsigned short* __restrict__ WhT, unsigned short* __restrict__ WfT,
    float* __restrict__ pf)
{
    __shared__ float ls[128 * 68];    // 34.8 KB
    __shared__ float red[64 * 4];
    const int bi = blockIdx.x, t = threadIdx.x;

    if (bi < 256) {
        const float* src = f0 + (size_t)bi * 8192;
#pragma unroll
        for (int i = 0; i < 8; ++i) {
            const int fi = (t + 256 * i) * 4;
            const int c = fi >> 6, r = fi & 63;      // in[c][r]
            *(float4*)(ls + c * 68 + r) = *(const float4*)(src + fi);
        }
        __syncthreads();

        const int w = t >> 6, lane = t & 63;
        const int m = lane & 15, g = lane >> 4;

        f32x4 acc[4];
#pragma unroll
        for (int nt = 0; nt < 4; ++nt) acc[nt] = (f32x4){0.f, 0.f, 0.f, 0.f};
#pragma unroll
        for (int kt = 0; kt < 4; ++kt) {
            s16x8 afr;
#pragma unroll
            for (int e = 0; e < 8; ++e)
                afr[e] = (short)f2bf(ls[(kt * 32 + g * 8 + e) * 68 + w * 16 + m]);
#pragma unroll
            for (int nt = 0; nt < 4; ++nt) {
                const float* wr = Wp + (size_t)(nt * 16 + m) * 128 + kt * 32 + g * 8;
                const float4 b0 = *(const float4*)wr;
                const float4 b1 = *(const float4*)(wr + 4);
                s16x8 bfr;
                bfr[0] = (short)f2bf(b0.x); bfr[1] = (short)f2bf(b0.y);
                bfr[2] = (short)f2bf(b0.z); bfr[3] = (short)f2bf(b0.w);
                bfr[4] = (short)f2bf(b1.x); bfr[5] = (short)f2bf(b1.y);
                bfr[6] = (short)f2bf(b1.z); bfr[7] = (short)f2bf(b1.w);
                acc[nt] = __builtin_amdgcn_mfma_f32_16x16x32_bf16(afr, bfr, acc[nt], 0, 0, 0);
            }
        }
        // WfT store, fragment-major
        unsigned short* D = WfT + (size_t)bi * 4096;
#pragma unroll
        for (int nt = 0; nt < 4; ++nt)
#pragma unroll
            for (int j = 0; j < 4; ++j) {
                const int Q = nt * 16 + m;
                const int N = (((Q >> 5) * 4 + w) * 64 + ((Q >> 3) & 3) * 16 + (g * 4 + j)) * 8 + (Q & 7);
                D[N] = f2bf(acc[nt][j]);
            }

        {
            const int r = t & 63, half = t >> 6;
            const int n0 = bi >> 2, q = bi & 3;
            const int pp = (2 * (n0 >> 3) + (q >> 1)) * GRID_P + 2 * (n0 & 7) + (q & 1);
            const float* posr = pos + (size_t)pp * C;
            float s = 0.f;
#pragma unroll 8
            for (int e = 0; e < 32; ++e) {
                const int c = half * 32 + e;
                s += (posr[c] + bp[c]) * ls[c * 68 + r];
            }
            red[r * 4 + half] = s;
        }
        __syncthreads();
        if (t < 64)
            pf[bi * 64 + t] = red[t * 4 + 0] + red[t * 4 + 1] + red[t * 4 + 2] + red[t * 4 + 3];
    } else if (bi < 340) {
        const int ti = bi - 256;
        const float* src;
        if      (ti < 64) src = f1 + (size_t)ti * 8192;
        else if (ti < 80) src = f2 + (size_t)(ti - 64) * 8192;
        else              src = f3 + (size_t)(ti - 80) * 8192;
        unsigned short* dst = fTL + (size_t)ti * 8192;
#pragma unroll
        for (int i = 0; i < 8; ++i) {
            const int fi = (t + 256 * i) * 4;
            const int c = fi >> 6, r = fi & 63;
            *(float4*)(ls + c * 68 + r) = *(const float4*)(src + fi);
        }
        __syncthreads();
        // ALL f-slices fragment-major [grp=kt*4+nt][lane][8]
#pragma unroll
        for (int k = 0; k < 4; ++k) {
            const int unit = t + 256 * k;      // 0..1023
            const int grp = unit >> 6, lp = unit & 63;
            const int kt = grp >> 2, nt = grp & 3;
            const int mp = lp & 15, gp = lp >> 4;
            s16x8 v;
#pragma unroll
            for (int e = 0; e < 8; ++e)
                v[e] = (short)f2bf(ls[(kt * 32 + gp * 8 + e) * 68 + nt * 16 + mp]);
            *(s16x8*)(dst + (size_t)(grp * 64 + lp) * 8) = v;
        }
    } else if (bi < 425) {
        const int oi = bi - 340;
        const float* src;
        if      (oi < 64) src = o0 + (size_t)oi * 8192;
        else if (oi < 80) src = o1 + (size_t)(oi - 64) * 8192;
        else if (oi < 84) src = o2 + (size_t)(oi - 80) * 8192;
        else              src = o3 + (size_t)(oi - 84) * 8192;
        unsigned short* dst = oT + (size_t)oi * 8192;
#pragma unroll
        for (int i = 0; i < 8; ++i) {
            const int fi = (t + 256 * i) * 4;
            const int r = fi >> 7, c = fi & 127;
            *(float4*)(ls + r * 132 + c) = *(const float4*)(src + fi);
        }
        __syncthreads();
        // ALL o-slices fragment-major [grp=ct*2+kt][lane][8]
#pragma unroll
        for (int k = 0; k < 4; ++k) {
            const int unit = t + 256 * k;      // 0..1023
            const int grp = unit >> 6, lp = unit & 63;
            const int ct = grp >> 1, kt = grp & 1;
            const int mp = lp & 15, gp = lp >> 4;
            s16x8 v;
#pragma unroll
            for (int e = 0; e < 8; ++e)
                v[e] = (short)f2bf(ls[(kt * 32 + gp * 8 + e) * 132 + ct * 16 + mp]);
            *(s16x8*)(dst + (size_t)(grp * 64 + lp) * 8) = v;
        }
    } else {
        const int j = bi - 425;
#pragma unroll
        for (int i = 0; i < 8; ++i) {
            const int fi = (t + 256 * i) * 4;
            const int c = fi >> 6, e = fi & 63;
            *(float4*)(ls + c * 68 + e) = *(const float4*)(Wh + (size_t)c * E + j * 64 + e);
        }
        __syncthreads();
        // WhT fragment-major: grp = w*32 + kt*8 + nt ; block j owns
        // w = j>>1, nt = (j&1)*4 + nt_lo  (e = j*64 + nt_lo*16 + m)
#pragma unroll
        for (int k = 0; k < 4; ++k) {
            const int unit = t + 256 * k;      // 0..1023
            const int gl = unit >> 6, lp = unit & 63;
            const int kt = gl >> 2, nt_lo = gl & 3;
            const int mp = lp & 15, gp = lp >> 4;
            s16x8 v;
#pragma unroll
            for (int e = 0; e < 8; ++e)
                v[e] = (short)f2bf(ls[(kt * 32 + gp * 8 + e) * 68 + nt_lo * 16 + mp]);
            const int wq = j >> 1;
            const int nt = (j & 1) * 4 + nt_lo;
            *(s16x8*)(WhT + (size_t)((wq * 32 + kt * 8 + nt) * 64 + lp) * 8) = v;
        }
    }
}

// ---------------------------------------------------------------------------
// Fused level0+level1: fragment-major weights (R7) + coalesced pixel LDS
// staging (x: 8 lines/instr vs 64 direct) + XCD swizzle (R6).
// LDS 79168 B -> 2 blocks/CU.
// ---------------------------------------------------------------------------
__global__ __launch_bounds__(256, 2) void level01_fused(
    const float* __restrict__ x,              // (B,1,128,128)
    const unsigned short* __restrict__ WfT,   // 256 slices, fragment-major
    const float* __restrict__ pf,             // (256 x 64) fp32
    const unsigned short* __restrict__ oT,    // all slices fragment-major
    const unsigned short* __restrict__ fT1,   // 64 slices, fragment-major
    unsigned short* __restrict__ h2)          // (16,B,128) bf16  [n1][batch][c]
{
    __shared__ __align__(16) unsigned short pixs[16 * 1026];    // 32832 B
    __shared__ __align__(16) float          us1[4 * 16 * 68];   // 17408 B
    __shared__ __align__(16) unsigned short ps0[4 * 16 * 72];   //  9216 B
    __shared__ __align__(16) unsigned short ps1[16 * 72];       //  2304 B
    __shared__ __align__(16) unsigned short h1s[4 * 16 * 136];  // 17408 B
    // total 79168 B -> 2 blocks/CU

    const int bi = blockIdx.x;
    const int n1 = ((bi & 7) << 1) | ((bi >> 3) & 1);     // R6 XCD swizzle
    const int btile = bi >> 4;
    const int t = threadIdx.x, w = t >> 6, lane = t & 63;
    const int m = lane & 15, g = lane >> 4;
    const int bt = btile * 16;

    const int y1g = n1 >> 2, x1g = n1 & 3;
    const int Ry0 = y1g * 32, Rx0 = x1g * 32;
    const int n0 = (2 * y1g + (w >> 1)) * 8 + 2 * x1g + (w & 1);

    // ---- stage pixel region: 16 iters, fully line-coalesced ----
#pragma unroll
    for (int i = 0; i < 16; ++i) {
        const int idx = i * 256 + t;
        const int c4 = idx & 7, rowg = (idx >> 3) & 31, bl = idx >> 8;
        const float4 p4 = *(const float4*)(x + ((size_t)(bt + bl) * IMG + Ry0 + rowg) * IMG + Rx0 + c4 * 4);
        uint2 v;
        v.x = (unsigned int)f2bf(p4.x) | ((unsigned int)f2bf(p4.y) << 16);
        v.y = (unsigned int)f2bf(p4.z) | ((unsigned int)f2bf(p4.w) << 16);
        *(uint2*)(pixs + bl * 1026 + rowg * 32 + c4 * 4) = v;
    }
    __syncthreads();

    // ---- level0 pixel A-fragments from LDS ----
    s16x8 a[4][2];
    {
        const int rbase = 16 * (w >> 1);
        const int cbase = 16 * (w & 1);
#pragma unroll
        for (int q = 0; q < 4; ++q) {
            const int rq = rbase + 8 * (q >> 1) + g;
            const int cc = cbase + 8 * (q & 1);
#pragma unroll
            for (int kt = 0; kt < 2; ++kt)
                a[q][kt] = *(const s16x8*)(pixs + m * 1026 + (rq + kt * 4) * 32 + cc);
        }
    }

    // ---- level0 u-phase (+pf init), all 4 quadrants in-wave ----
    f32x4 accu[4][4];
#pragma unroll
    for (int q = 0; q < 4; ++q) {
        const float* pfq = pf + (size_t)(n0 * 4 + q) * 64;
#pragma unroll
        for (int nt = 0; nt < 4; ++nt) {
            const float pv = pfq[nt * 16 + m];
            accu[q][nt] = (f32x4){pv, pv, pv, pv};
        }
    }
#pragma unroll
    for (int q = 0; q < 4; ++q) {
        const unsigned short* Wq = WfT + (size_t)(n0 * 4 + q) * 4096;
#pragma unroll
        for (int kt = 0; kt < 2; ++kt) {
#pragma unroll
            for (int nt = 0; nt < 4; ++nt) {
                const s16x8 bfr = *(const s16x8*)(Wq + (size_t)((kt * 4 + nt) * 64 + lane) * 8);
                accu[q][nt] = __builtin_amdgcn_mfma_f32_16x16x32_bf16(a[q][kt], bfr, accu[q][nt], 0, 0, 0);
            }
        }
    }

    // ---- level0 p-phase (regs) + wave-private ps roundtrip ----
    unsigned short* myps = ps0 + w * (16 * 72);
#pragma unroll
    for (int nt = 0; nt < 4; ++nt) {
        const f32x4 pr = accu[0][nt] * accu[1][nt] * accu[2][nt] * accu[3][nt];
#pragma unroll
        for (int j = 0; j < 4; ++j)
            myps[(g * 4 + j) * 72 + nt * 16 + m] = f2bf(pr[j]);
    }

    // ---- level0 o-phase (in-wave) -> h1 tile in wave-private LDS ----
    {
        s16x8 ap[2];
#pragma unroll
        for (int kt = 0; kt < 2; ++kt)
            ap[kt] = *(const s16x8*)(myps + m * 72 + kt * 32 + g * 8);
        const unsigned short* oTn = oT + (size_t)n0 * 8192;
        unsigned short* myh = h1s + w * (16 * 136);
#pragma unroll
        for (int ct = 0; ct < 8; ++ct) {
            f32x4 aco = (f32x4){0.f, 0.f, 0.f, 0.f};
#pragma unroll
            for (int kt = 0; kt < 2; ++kt) {
                const s16x8 bfr = *(const s16x8*)(oTn + (size_t)((ct * 2 + kt) * 64 + lane) * 8);
                aco = __builtin_amdgcn_mfma_f32_16x16x32_bf16(ap[kt], bfr, aco, 0, 0, 0);
            }
#pragma unroll
            for (int j = 0; j < 4; ++j)
                myh[(g * 4 + j) * 136 + ct * 16 + m] = f2bf(aco[j]);
        }
    }

    // ---- level1 u-phase: A = own h1 tile (wave-private, no barrier) ----
    {
        const unsigned short* myh = h1s + w * (16 * 136);
        const unsigned short* fq = fT1 + (size_t)(n1 * 4 + w) * 8192;
        f32x4 au[4];
#pragma unroll
        for (int nt = 0; nt < 4; ++nt) au[nt] = (f32x4){0.f, 0.f, 0.f, 0.f};
#pragma unroll
        for (int kt = 0; kt < 4; ++kt) {
            const int koff = kt * 32 + g * 8;
            const s16x8 afr = *(const s16x8*)(myh + m * 136 + koff);
#pragma unroll
            for (int nt = 0; nt < 4; ++nt) {
                const s16x8 bfr = *(const s16x8*)(fq + (size_t)((kt * 4 + nt) * 64 + lane) * 8);
                au[nt] = __builtin_amdgcn_mfma_f32_16x16x32_bf16(afr, bfr, au[nt], 0, 0, 0);
            }
        }
#pragma unroll
        for (int nt = 0; nt < 4; ++nt)
#pragma unroll
            for (int j = 0; j < 4; ++j)
                us1[(w * 16 + g * 4 + j) * 68 + nt * 16 + m] = au[nt][j];
    }
    __syncthreads();

    // ---- level1 p-phase (block-wide) ----
    {
        const int pb = t >> 4, r0 = (t & 15) * 4;
        const f32x4 u0 = *(const f32x4*)(us1 + (0 * 16 + pb) * 68 + r0);
        const f32x4 u1 = *(const f32x4*)(us1 + (1 * 16 + pb) * 68 + r0);
        const f32x4 u2 = *(const f32x4*)(us1 + (2 * 16 + pb) * 68 + r0);
        const f32x4 u3 = *(const f32x4*)(us1 + (3 * 16 + pb) * 68 + r0);
        const f32x4 p = u0 * u1 * u2 * u3;
        uint2 v;
        v.x = (unsigned int)f2bf(p[0]) | ((unsigned int)f2bf(p[1]) << 16);
        v.y = (unsigned int)f2bf(p[2]) | ((unsigned int)f2bf(p[3]) << 16);
        *(uint2*)(ps1 + pb * 72 + r0) = v;
    }
    __syncthreads();

    // ---- level1 o-phase: wave handles ct = 2w, 2w+1 -> h2 [n1][batch][c] --
    {
        s16x8 ap[2];
#pragma unroll
        for (int kt = 0; kt < 2; ++kt)
            ap[kt] = *(const s16x8*)(ps1 + m * 72 + kt * 32 + g * 8);
        const unsigned short* oTn = oT + (size_t)(64 + n1) * 8192;
#pragma unroll
        for (int i = 0; i < 2; ++i) {
            const int ct = w * 2 + i;
            f32x4 aco = (f32x4){0.f, 0.f, 0.f, 0.f};
#pragma unroll
            for (int kt = 0; kt < 2; ++kt) {
                const s16x8 bfr = *(const s16x8*)(oTn + (size_t)((ct * 2 + kt) * 64 + lane) * 8);
                aco = __builtin_amdgcn_mfma_f32_16x16x32_bf16(ap[kt], bfr, aco, 0, 0, 0);
            }
#pragma unroll
            for (int j = 0; j < 4; ++j)
                h2[((size_t)n1 * BATCH + (bt + g * 4 + j)) * C + ct * 16 + m] = f2bf(aco[j]);
        }
    }
}

// ---------------------------------------------------------------------------
// Tail: level2 + level3 + LayerNorm + head + L2norm, block = 16 batches.
// All weight reads fragment-major (1KB contiguous wave reads); h2 reads
// from [n1][batch][c] layout.
// ---------------------------------------------------------------------------
__global__ __launch_bounds__(256, 1) void tail_kernel(
    const unsigned short* __restrict__ h2,    // (16,B,128) bf16
    const unsigned short* __restrict__ fT2,   // 16 slices, fragment-major
    const unsigned short* __restrict__ oT2,   // 4 slices, fragment-major
    const unsigned short* __restrict__ fT3,   // 4 slices, fragment-major
    const unsigned short* __restrict__ oT3,   // 1 slice, fragment-major
    const float* __restrict__ gamma, const float* __restrict__ beta,
    const unsigned short* __restrict__ WhT,   // fragment-major
    const float* __restrict__ bh,             // (512)
    float* __restrict__ out)                  // (B,512) fp32
{
    __shared__ __align__(16) float          us3[4 * 16 * 68];
    __shared__ __align__(16) unsigned short ps2[4 * 16 * 72];
    __shared__ __align__(16) unsigned short ps3[16 * 72];
    __shared__ __align__(16) unsigned short h3s[16 * 4 * 136];
    __shared__ __align__(16) float          h4s[16 * 132];
    __shared__ __align__(16) unsigned short hns[16 * 136];
    __shared__ float red[16 * 4];

    const int bt = blockIdx.x * 16;
    const int t = threadIdx.x, w = t >> 6, lane = t & 63;
    const int m = lane & 15, g = lane >> 4;

    // ===== Level 2: wave w = node n2 =====
    {
        const int n2 = w;
        const int y1 = n2 >> 1, x1 = n2 & 1;

        // prefetch all A-fragments (chain head; h2 [n1][batch][c])
        s16x8 xa[4][4];    // [q][kt]
#pragma unroll
        for (int q = 0; q < 4; ++q) {
            const int pidx = (2 * y1 + (q >> 1)) * 4 + 2 * x1 + (q & 1);
            const unsigned short* xq = h2 + ((size_t)pidx * BATCH + bt + m) * C;
#pragma unroll
            for (int kt = 0; kt < 4; ++kt)
                xa[q][kt] = *(const s16x8*)(xq + kt * 32 + g * 8);
        }

        f32x4 acc_u[4][4];
#pragma unroll
        for (int q = 0; q < 4; ++q)
#pragma unroll
            for (int nt = 0; nt < 4; ++nt) acc_u[q][nt] = (f32x4){0.f, 0.f, 0.f, 0.f};
#pragma unroll
        for (int q = 0; q < 4; ++q) {
            const unsigned short* fq = fT2 + (size_t)(n2 * 4 + q) * 8192;
#pragma unroll
            for (int kt = 0; kt < 4; ++kt) {
#pragma unroll
                for (int nt = 0; nt < 4; ++nt) {
                    const s16x8 bfr = *(const s16x8*)(fq + (size_t)((kt * 4 + nt) * 64 + lane) * 8);
                    acc_u[q][nt] = __builtin_amdgcn_mfma_f32_16x16x32_bf16(xa[q][kt], bfr, acc_u[q][nt], 0, 0, 0);
                }
            }
        }

        // prefetch o-phase B-fragments
        s16x8 ob[8][2];
        {
            const unsigned short* oTn = oT2 + (size_t)n2 * 8192;
#pragma unroll
            for (int ct = 0; ct < 8; ++ct)
#pragma unroll
                for (int kt = 0; kt < 2; ++kt)
                    ob[ct][kt] = *(const s16x8*)(oTn + (size_t)((ct * 2 + kt) * 64 + lane) * 8);
        }

        unsigned short* myps2 = ps2 + w * 16 * 72;
#pragma unroll
        for (int nt = 0; nt < 4; ++nt) {
            const f32x4 p = acc_u[0][nt] * acc_u[1][nt] * acc_u[2][nt] * acc_u[3][nt];
#pragma unroll
            for (int j = 0; j < 4; ++j)
                myps2[(g * 4 + j) * 72 + nt * 16 + m] = f2bf(p[j]);
        }
        f32x4 aco[8];
#pragma unroll
        for (int ct = 0; ct < 8; ++ct) aco[ct] = (f32x4){0.f, 0.f, 0.f, 0.f};
#pragma unroll
        for (int kt = 0; kt < 2; ++kt) {
            const int koff = kt * 32 + g * 8;
            const s16x8 av = *(const s16x8*)(myps2 + m * 72 + koff);
#pragma unroll
            for (int ct = 0; ct < 8; ++ct)
                aco[ct] = __builtin_amdgcn_mfma_f32_16x16x32_bf16(av, ob[ct][kt], aco[ct], 0, 0, 0);
        }
#pragma unroll
        for (int ct = 0; ct < 8; ++ct)
#pragma unroll
            for (int j = 0; j < 4; ++j)
                h3s[((g * 4 + j) * 4 + n2) * 136 + ct * 16 + m] = f2bf(aco[ct][j]);
    }
    __syncthreads();

    // ===== Level 3: wave w = quadrant q =====
    {
        const int q = w;
        s16x8 fb[4][4];   // [kt][nt]
        {
            const unsigned short* fq = fT3 + (size_t)q * 8192;
#pragma unroll
            for (int kt = 0; kt < 4; ++kt)
#pragma unroll
                for (int nt = 0; nt < 4; ++nt)
                    fb[kt][nt] = *(const s16x8*)(fq + (size_t)((kt * 4 + nt) * 64 + lane) * 8);
        }
        f32x4 acc_u[4];
#pragma unroll
        for (int nt = 0; nt < 4; ++nt) acc_u[nt] = (f32x4){0.f, 0.f, 0.f, 0.f};
#pragma unroll
        for (int kt = 0; kt < 4; ++kt) {
            const int koff = kt * 32 + g * 8;
            const s16x8 av = *(const s16x8*)(h3s + (m * 4 + q) * 136 + koff);
#pragma unroll
            for (int nt = 0; nt < 4; ++nt)
                acc_u[nt] = __builtin_amdgcn_mfma_f32_16x16x32_bf16(av, fb[kt][nt], acc_u[nt], 0, 0, 0);
        }
#pragma unroll
        for (int nt = 0; nt < 4; ++nt)
#pragma unroll
            for (int j = 0; j < 4; ++j)
                us3[(q * 16 + g * 4 + j) * 68 + nt * 16 + m] = acc_u[nt][j];
    }
    __syncthreads();
    {
        const int pb = t >> 4, r0 = (t & 15) * 4;
        const f32x4 u0 = *(const f32x4*)(us3 + (0 * 16 + pb) * 68 + r0);
        const f32x4 u1 = *(const f32x4*)(us3 + (1 * 16 + pb) * 68 + r0);
        const f32x4 u2 = *(const f32x4*)(us3 + (2 * 16 + pb) * 68 + r0);
        const f32x4 u3 = *(const f32x4*)(us3 + (3 * 16 + pb) * 68 + r0);
        const f32x4 p = u0 * u1 * u2 * u3;
        uint2 v;
        v.x = (unsigned int)f2bf(p[0]) | ((unsigned int)f2bf(p[1]) << 16);
        v.y = (unsigned int)f2bf(p[2]) | ((unsigned int)f2bf(p[3]) << 16);
        *(uint2*)(ps3 + pb * 72 + r0) = v;
    }
    __syncthreads();
    {
        s16x8 ap[2];
#pragma unroll
        for (int kt = 0; kt < 2; ++kt)
            ap[kt] = *(const s16x8*)(ps3 + m * 72 + kt * 32 + g * 8);
#pragma unroll
        for (int i = 0; i < 2; ++i) {
            f32x4 aco = (f32x4){0.f, 0.f, 0.f, 0.f};
            const int ct = w * 2 + i;
#pragma unroll
            for (int kt = 0; kt < 2; ++kt) {
                const s16x8 bfr = *(const s16x8*)(oT3 + (size_t)((ct * 2 + kt) * 64 + lane) * 8);
                aco = __builtin_amdgcn_mfma_f32_16x16x32_bf16(ap[kt], bfr, aco, 0, 0, 0);
            }
#pragma unroll
            for (int j = 0; j < 4; ++j)
                h4s[(g * 4 + j) * 132 + ct * 16 + m] = aco[j];
        }
    }
    __syncthreads();

    // ===== LayerNorm =====
    {
        const int rb = w * 4 + g;
        const int c0 = m * 8;
        const f32x4 v0 = *(const f32x4*)(h4s + rb * 132 + c0);
        const f32x4 v1 = *(const f32x4*)(h4s + rb * 132 + c0 + 4);
        float s  = v0[0] + v0[1] + v0[2] + v0[3] + v1[0] + v1[1] + v1[2] + v1[3];
        float ss = v0[0]*v0[0] + v0[1]*v0[1] + v0[2]*v0[2] + v0[3]*v0[3]
                 + v1[0]*v1[0] + v1[1]*v1[1] + v1[2]*v1[2] + v1[3]*v1[3];
#pragma unroll
        for (int off = 1; off < 16; off <<= 1) {
            s  += __shfl_xor(s, off);
            ss += __shfl_xor(ss, off);
        }
        const float mu   = s * (1.f / C);
        const float var  = ss * (1.f / C) - mu * mu;
        const float rstd = rsqrtf(var + 1e-5f);
        const f32x4 ga0 = *(const f32x4*)(gamma + c0);
        const f32x4 ga1 = *(const f32x4*)(gamma + c0 + 4);
        const f32x4 be0 = *(const f32x4*)(beta + c0);
        const f32x4 be1 = *(const f32x4*)(beta + c0 + 4);
        unsigned int o32[4];
        float hv[8];
#pragma unroll
        for (int k = 0; k < 4; ++k) hv[k]     = (v0[k] - mu) * rstd * ga0[k] + be0[k];
#pragma unroll
        for (int k = 0; k < 4; ++k) hv[4 + k] = (v1[k] - mu) * rstd * ga1[k] + be1[k];
#pragma unroll
        for (int k = 0; k < 4; ++k)
            o32[k] = (unsigned int)f2bf(hv[2*k]) | ((unsigned int)f2bf(hv[2*k+1]) << 16);
        *(uint4*)(hns + rb * 136 + c0) = *(uint4*)o32;
    }
    __syncthreads();

    // ===== Head GEMM + L2 norm =====
    {
        f32x4 acc[8];
#pragma unroll
        for (int nt = 0; nt < 8; ++nt) {
            const int e = w * 128 + nt * 16 + m;
            const float bv = bh[e];
            acc[nt] = (f32x4){bv, bv, bv, bv};
        }
#pragma unroll
        for (int kt = 0; kt < 4; ++kt) {
            const int koff = kt * 32 + g * 8;
            const s16x8 av = *(const s16x8*)(hns + m * 136 + koff);
#pragma unroll
            for (int nt = 0; nt < 8; ++nt) {
                const s16x8 bfr = *(const s16x8*)(WhT + (size_t)((w * 32 + kt * 8 + nt) * 64 + lane) * 8);
                acc[nt] = __builtin_amdgcn_mfma_f32_16x16x32_bf16(av, bfr, acc[nt], 0, 0, 0);
            }
        }
        float sq[4];
#pragma unroll
        for (int j = 0; j < 4; ++j) {
            float s = 0.f;
#pragma unroll
            for (int nt = 0; nt < 8; ++nt) s += acc[nt][j] * acc[nt][j];
#pragma unroll
            for (int off = 1; off < 16; off <<= 1) s += __shfl_xor(s, off);
            sq[j] = s;
        }
        if (m == 0) {
#pragma unroll
            for (int j = 0; j < 4; ++j) red[(g * 4 + j) * 4 + w] = sq[j];
        }
        __syncthreads();
#pragma unroll
        for (int j = 0; j < 4; ++j) {
            const int row = g * 4 + j;
            const float tot = red[row * 4 + 0] + red[row * 4 + 1]
                            + red[row * 4 + 2] + red[row * 4 + 3];
            const float inv = 1.f / fmaxf(sqrtf(tot), 1e-12f);
#pragma unroll
            for (int nt = 0; nt < 8; ++nt) {
                const int e = w * 128 + nt * 16 + m;
                out[(size_t)(bt + row) * E + e] = acc[nt][j] * inv;
            }
        }
    }
}

// ---------------------------------------------------------------------------
extern "C" void kernel_launch(void* const* d_in, const int* in_sizes, int n_in,
                              void* d_out, int out_size, void* d_ws, size_t ws_size,
                              hipStream_t stream) {
    const float* x     = (const float*)d_in[0];
    const float* Wp    = (const float*)d_in[1];
    const float* bp    = (const float*)d_in[2];
    const float* pos   = (const float*)d_in[3];
    const float* gamma = (const float*)d_in[4];
    const float* beta  = (const float*)d_in[5];
    const float* Wh    = (const float*)d_in[6];
    const float* bh    = (const float*)d_in[7];
    const float* f0    = (const float*)d_in[8];
    const float* o0    = (const float*)d_in[9];
    const float* f1    = (const float*)d_in[10];
    const float* o1    = (const float*)d_in[11];
    const float* f2    = (const float*)d_in[12];
    const float* o2    = (const float*)d_in[13];
    const float* f3    = (const float*)d_in[14];
    const float* o3    = (const float*)d_in[15];
    float* out = (float*)d_out;

    // workspace layout (bf16 elements unless noted)
    unsigned short* h2  = (unsigned short*)d_ws;          // 1,048,576
    unsigned short* fTL = h2 + (size_t)1048576;           //   688,128 (84 slices)
    unsigned short* oT  = fTL + (size_t)688128;           //   696,320 (85 slices)
    unsigned short* WfT = oT + (size_t)696320;            // 1,048,576 (256 x 64x64)
    unsigned short* WhT = WfT + (size_t)1048576;          //    65,536
    float*          pff = (float*)(WhT + 65536);          //    16,384 fp32

    unsigned short* fT1 = fTL;
    unsigned short* fT2 = fTL + (size_t)64 * 8192;
    unsigned short* fT3 = fTL + (size_t)80 * 8192;
    unsigned short* oT2 = oT + (size_t)80 * 8192;
    unsigned short* oT3 = oT + (size_t)84 * 8192;

    prep_all_kernel<<<433, 256, 0, stream>>>(f0, f1, f2, f3, o0, o1, o2, o3,
                                             Wh, Wp, pos, bp,
                                             fTL, oT, WhT, WfT, pff);

    level01_fused<<<16 * 32, 256, 0, stream>>>(x, WfT, pff, oT, fT1, h2);

    tail_kernel<<<32, 256, 0, stream>>>(h2, fT2, oT2, fT3, oT3,
                                        gamma, beta, WhT, bh, out);
}